// Round 21
// baseline (239.249 us; speedup 1.0000x reference)
//
#include <hip/hip_runtime.h>
#include <math.h>

#define Bsz 4
#define Tt  1024
#define Cc  1024
#define Hh  16
#define HSs 64
#define CL  32            // wkv chunk length
#define NCH (Tt / CL)     // 32 chunks
#define STRD 260          // fp32 step stride (4 arrays x 64 + 4 pad)

typedef __attribute__((ext_vector_type(8))) short bf16x8;
typedef __attribute__((ext_vector_type(4))) float f32x4;

__device__ __forceinline__ float sigf(float x) { return 1.f / (1.f + expf(-x)); }

__device__ __forceinline__ unsigned short f2bf(float f) {
    unsigned int u = __float_as_uint(f);
    u = u + 0x7fffu + ((u >> 16) & 1u);   // RNE
    return (unsigned short)(u >> 16);
}
__device__ __forceinline__ float bf2f(unsigned short u) {
    return __uint_as_float(((unsigned int)u) << 16);
}
__device__ __forceinline__ float dpp_add_xor1(float x) {
    int y = __builtin_amdgcn_mov_dpp(__float_as_int(x), 0xB1, 0xF, 0xF, true);
    return x + __int_as_float(y);
}
__device__ __forceinline__ float dpp_add_xor2(float x) {
    int y = __builtin_amdgcn_mov_dpp(__float_as_int(x), 0x4E, 0xF, 0xF, true);
    return x + __int_as_float(y);
}

// async global->LDS, 16B per lane; lds must be wave-uniform base
__device__ __forceinline__ void gload16(const void* g, void* l) {
    __builtin_amdgcn_global_load_lds(
        (const __attribute__((address_space(1))) unsigned int*)g,
        (__attribute__((address_space(3))) unsigned int*)l, 16, 0, 0);
}

// unpack 8 packed bf16 (uint4) into dst[off..off+7]
#define UNPK8(dst, u4, off) do { \
    const unsigned int* q_ = (const unsigned int*)&(u4); \
    _Pragma("unroll") \
    for (int e_ = 0; e_ < 4; ++e_) { \
        (dst)[(off) + 2 * e_]     = __uint_as_float(q_[e_] << 16); \
        (dst)[(off) + 2 * e_ + 1] = __uint_as_float(q_[e_] & 0xFFFF0000u); \
    } \
} while (0)

// ---------------------------------------------------------------------------
// 64x64 transpose+cast helper
// ---------------------------------------------------------------------------
__device__ __forceinline__ void tcast64(
    const float* __restrict__ W, unsigned short* __restrict__ WT,
    int K, int N, int n0, int k0, int tid, unsigned short tile[64][68])
{
    const int tr = tid >> 4, tc4 = (tid & 15) * 4;
#pragma unroll
    for (int s = 0; s < 4; ++s) {
        int kk = tr + s * 16;
        float4 w4 = *(const float4*)(W + (size_t)(k0 + kk) * N + n0 + tc4);
        tile[kk][tc4 + 0] = f2bf(w4.x);
        tile[kk][tc4 + 1] = f2bf(w4.y);
        tile[kk][tc4 + 2] = f2bf(w4.z);
        tile[kk][tc4 + 3] = f2bf(w4.w);
    }
    __syncthreads();
#pragma unroll
    for (int s = 0; s < 4; ++s) {
        int nn = tr + s * 16;
        ushort4 o4;
        o4.x = tile[tc4 + 0][nn];
        o4.y = tile[tc4 + 1][nn];
        o4.z = tile[tc4 + 2][nn];
        o4.w = tile[tc4 + 3][nn];
        *(ushort4*)(WT + (size_t)(n0 + nn) * K + k0 + tc4) = o4;
    }
}

// ---------------------------------------------------------------------------
// prep_all: mixcast (blocks 0..4095) + 10 weight transposes
// ---------------------------------------------------------------------------
__global__ __launch_bounds__(256) void prep_all(
    const float* __restrict__ x, const float* __restrict__ x_r,
    const float* __restrict__ x_k, const float* __restrict__ x_v,
    const float* __restrict__ Wr, const float* __restrict__ Wk,
    const float* __restrict__ Wv, const float* __restrict__ Wo,
    const float* __restrict__ w1, const float* __restrict__ a1,
    const float* __restrict__ g1, const float* __restrict__ w2,
    const float* __restrict__ a2, const float* __restrict__ g2,
    unsigned short* __restrict__ xr, unsigned short* __restrict__ xk,
    unsigned short* __restrict__ xvo,
    unsigned short* __restrict__ WrT, unsigned short* __restrict__ WkT,
    unsigned short* __restrict__ WvT, unsigned short* __restrict__ WoT,
    unsigned short* __restrict__ w1t, unsigned short* __restrict__ a1t,
    unsigned short* __restrict__ g1t, unsigned short* __restrict__ w2t,
    unsigned short* __restrict__ a2t, unsigned short* __restrict__ g2t)
{
    __shared__ unsigned short tile[64][68];
    const int tid = threadIdx.x;
    int bid = blockIdx.x;

    if (bid < 4096) {
        const int row = bid;
        const int c0 = tid * 4;
        const size_t o = (size_t)row * Cc;
        float4 xc = *(const float4*)(x + o + c0);
        float4 xp;
        if (row & (Tt - 1)) xp = *(const float4*)(x + o - Cc + c0);
        else { xp.x = xp.y = xp.z = xp.w = 0.f; }
        float4 mr = *(const float4*)(x_r + c0);
        float4 mk = *(const float4*)(x_k + c0);
        float4 mv = *(const float4*)(x_v + c0);
        const float* xcf = (const float*)&xc; const float* xpf = (const float*)&xp;
        const float* mrf = (const float*)&mr; const float* mkf = (const float*)&mk;
        const float* mvf = (const float*)&mv;
        ushort4 r4, k4, v4;
        unsigned short* rp = (unsigned short*)&r4;
        unsigned short* kp = (unsigned short*)&k4;
        unsigned short* vp = (unsigned short*)&v4;
#pragma unroll
        for (int j = 0; j < 4; ++j) {
            float xx = xpf[j] - xcf[j];
            rp[j] = f2bf(xcf[j] + xx * mrf[j]);
            kp[j] = f2bf(xcf[j] + xx * mkf[j]);
            vp[j] = f2bf(xcf[j] + xx * mvf[j]);
        }
        *(ushort4*)(xr + o + c0) = r4;
        *(ushort4*)(xk + o + c0) = k4;
        *(ushort4*)(xvo + o + c0) = v4;
        return;
    }
    bid -= 4096;
    if (bid < 1024) {
        int which = bid >> 8, id0 = bid & 255;
        const float* W = which == 0 ? Wr : which == 1 ? Wk : which == 2 ? Wv : Wo;
        unsigned short* WT = which == 0 ? WrT : which == 1 ? WkT : which == 2 ? WvT : WoT;
        tcast64(W, WT, Cc, Cc, (id0 & 15) * 64, (id0 >> 4) * 64, tid, tile);
        return;
    }
    bid -= 1024;
    if (bid < 16) { tcast64(w1, w1t, Cc, 64, 0, bid * 64, tid, tile); return; }
    bid -= 16;
    if (bid < 16) { tcast64(a1, a1t, Cc, 64, 0, bid * 64, tid, tile); return; }
    bid -= 16;
    if (bid < 32) { tcast64(g1, g1t, Cc, 128, (bid & 1) * 64, (bid >> 1) * 64, tid, tile); return; }
    bid -= 32;
    if (bid < 16) { tcast64(w2, w2t, 64, Cc, bid * 64, 0, tid, tile); return; }
    bid -= 16;
    if (bid < 16) { tcast64(a2, a2t, 64, Cc, bid * 64, 0, tid, tile); return; }
    bid -= 16;
    tcast64(g2, g2t, 128, Cc, (bid & 15) * 64, (bid >> 4) * 64, tid, tile);
}

// ---------------------------------------------------------------------------
// big bf16 MFMA GEMM, r/k/v fused (z). All outputs bf16. XCD-swizzled blockIdx.
// ---------------------------------------------------------------------------
__global__ __launch_bounds__(256) void gemm_rkv(
    const unsigned short* __restrict__ xr, const unsigned short* __restrict__ xk,
    const unsigned short* __restrict__ xv,
    const unsigned short* __restrict__ WrT, const unsigned short* __restrict__ WkT,
    const unsigned short* __restrict__ WvT,
    unsigned short* __restrict__ rbh, unsigned short* __restrict__ kbh,
    unsigned short* __restrict__ vbh)
{
    const int z = blockIdx.z;
    const unsigned short* A  = z == 0 ? xr : z == 1 ? xk : xv;
    const unsigned short* WT = z == 0 ? WrT : z == 1 ? WkT : WvT;
    unsigned short* outh = z == 0 ? rbh : z == 1 ? kbh : vbh;
    const int K = Cc, N = Cc;

    const int bid = blockIdx.x + 8 * blockIdx.y;      // 0..255
    const int swz = (bid & 7) * 32 + (bid >> 3);
    const int row0 = (swz >> 3) * 128;
    const int col0 = (swz & 7) * 128;

    __shared__ __attribute__((aligned(16))) unsigned short As[128 * 32];
    __shared__ __attribute__((aligned(16))) unsigned short Bs[128 * 32];
    const int tid = threadIdx.x;
    const int wave = tid >> 6, lane = tid & 63;
    const int wr = wave >> 1, wc = wave & 1;
    const int lr = lane & 15, lk = lane >> 4;

    f32x4 acc[4][4];
#pragma unroll
    for (int m = 0; m < 4; ++m)
#pragma unroll
        for (int n = 0; n < 4; ++n)
#pragma unroll
            for (int r = 0; r < 4; ++r) acc[m][n][r] = 0.f;

    const int lrow = lane >> 2;
    const int lcol8 = (lane & 3) * 8;

    for (int k0 = 0; k0 < K; k0 += 32) {
#pragma unroll
        for (int e = 0; e < 2; ++e) {
            int cib = wave * 128 + e * 64;
            int row = (cib >> 2) + lrow;
            gload16(A  + (size_t)(row0 + row) * K + k0 + lcol8, &As[cib * 8]);
            gload16(WT + (size_t)(col0 + row) * K + k0 + lcol8, &Bs[cib * 8]);
        }
        __syncthreads();
        bf16x8 af[4], bff[4];
#pragma unroll
        for (int m = 0; m < 4; ++m)
            af[m] = *(const bf16x8*)&As[(wr * 64 + m * 16 + lr) * 32 + lk * 8];
#pragma unroll
        for (int n = 0; n < 4; ++n)
            bff[n] = *(const bf16x8*)&Bs[(wc * 64 + n * 16 + lr) * 32 + lk * 8];
#pragma unroll
        for (int m = 0; m < 4; ++m)
#pragma unroll
            for (int n = 0; n < 4; ++n)
                acc[m][n] = __builtin_amdgcn_mfma_f32_16x16x32_bf16(af[m], bff[n], acc[m][n], 0, 0, 0);
        __syncthreads();
    }

#pragma unroll
    for (int m = 0; m < 4; ++m)
#pragma unroll
        for (int n = 0; n < 4; ++n) {
            int col = col0 + wc * 64 + n * 16 + lr;
#pragma unroll
            for (int r = 0; r < 4; ++r) {
                int row = row0 + wr * 64 + m * 16 + lk * 4 + r;
                outh[(size_t)row * N + col] = f2bf(acc[m][n][r]);
            }
        }
}

// ---------------------------------------------------------------------------
// plain 128x128 bf16 GEMM (Wo projection), XCD-swizzled
// ---------------------------------------------------------------------------
__global__ __launch_bounds__(256) void gemm_bf16(
    const unsigned short* __restrict__ A, const unsigned short* __restrict__ WT,
    float* __restrict__ out, int M, int N, int K)
{
    __shared__ __attribute__((aligned(16))) unsigned short As[128 * 32];
    __shared__ __attribute__((aligned(16))) unsigned short Bs[128 * 32];
    const int bid = blockIdx.x + 8 * blockIdx.y;      // 0..255
    const int swz = (bid & 7) * 32 + (bid >> 3);
    const int row0 = (swz >> 3) * 128;
    const int col0 = (swz & 7) * 128;
    const int tid = threadIdx.x;
    const int wave = tid >> 6, lane = tid & 63;
    const int wr = wave >> 1, wc = wave & 1;
    const int lr = lane & 15, lk = lane >> 4;

    f32x4 acc[4][4];
#pragma unroll
    for (int m = 0; m < 4; ++m)
#pragma unroll
        for (int n = 0; n < 4; ++n)
#pragma unroll
            for (int r = 0; r < 4; ++r) acc[m][n][r] = 0.f;

    const int lrow = lane >> 2;
    const int lcol8 = (lane & 3) * 8;

    for (int k0 = 0; k0 < K; k0 += 32) {
#pragma unroll
        for (int e = 0; e < 2; ++e) {
            int cib = wave * 128 + e * 64;
            int row = (cib >> 2) + lrow;
            gload16(A  + (size_t)(row0 + row) * K + k0 + lcol8, &As[cib * 8]);
            gload16(WT + (size_t)(col0 + row) * K + k0 + lcol8, &Bs[cib * 8]);
        }
        __syncthreads();
        bf16x8 af[4], bff[4];
#pragma unroll
        for (int m = 0; m < 4; ++m)
            af[m] = *(const bf16x8*)&As[(wr * 64 + m * 16 + lr) * 32 + lk * 8];
#pragma unroll
        for (int n = 0; n < 4; ++n)
            bff[n] = *(const bf16x8*)&Bs[(wc * 64 + n * 16 + lr) * 32 + lk * 8];
#pragma unroll
        for (int m = 0; m < 4; ++m)
#pragma unroll
            for (int n = 0; n < 4; ++n)
                acc[m][n] = __builtin_amdgcn_mfma_f32_16x16x32_bf16(af[m], bff[n], acc[m][n], 0, 0, 0);
        __syncthreads();
    }

#pragma unroll
    for (int m = 0; m < 4; ++m)
#pragma unroll
        for (int n = 0; n < 4; ++n) {
            int col = col0 + wc * 64 + n * 16 + lr;
#pragma unroll
            for (int r = 0; r < 4; ++r) {
                int row = row0 + wr * 64 + m * 16 + lk * 4 + r;
                out[(size_t)row * N + col] = acc[m][n][r];
            }
        }
}

// ---------------------------------------------------------------------------
// stage-1 low-rank MFMA, fused (seg on blockIdx.x) — BM=64 for grid-fill
// ---------------------------------------------------------------------------
__global__ __launch_bounds__(256) void lowrank1_fused(
    const float* __restrict__ x,
    const float* __restrict__ x_w, const float* __restrict__ x_a,
    const float* __restrict__ x_g,
    const unsigned short* __restrict__ w1t, const unsigned short* __restrict__ a1t,
    const unsigned short* __restrict__ g1t,
    unsigned short* __restrict__ hw, unsigned short* __restrict__ ha,
    unsigned short* __restrict__ hg)
{
    const int seg = blockIdx.x;
    const float* mix; const unsigned short* WT; unsigned short* out;
    int N, col0, epi;
    if (seg == 0)      { mix = x_w; WT = w1t; out = hw; N = 64;  col0 = 0; epi = 1; }
    else if (seg == 1) { mix = x_a; WT = a1t; out = ha; N = 64;  col0 = 0; epi = 0; }
    else               { mix = x_g; WT = g1t; out = hg; N = 128; col0 = (seg - 2) * 64; epi = 2; }

    __shared__ __attribute__((aligned(16))) unsigned short As[64][40];
    __shared__ __attribute__((aligned(16))) unsigned short Bs[64][40];
    const int row0 = blockIdx.y * 64;
    const int tid = threadIdx.x;
    const int wave = tid >> 6, lane = tid & 63;
    const int lr = lane & 15, lk = lane >> 4;

    f32x4 acc[4];
#pragma unroll
    for (int n = 0; n < 4; ++n)
#pragma unroll
        for (int r = 0; r < 4; ++r) acc[n][r] = 0.f;

    for (int k0 = 0; k0 < Cc; k0 += 32) {
        {
            int ar = tid >> 2, ac = (tid & 3) * 8;
            int row = row0 + ar;
            const float* xp = x + (size_t)row * Cc + k0 + ac;
            float4 c0 = *(const float4*)xp;
            float4 c1 = *(const float4*)(xp + 4);
            float4 p0, p1;
            if (row & (Tt - 1)) {
                p0 = *(const float4*)(xp - Cc);
                p1 = *(const float4*)(xp - Cc + 4);
            } else {
                p0.x = p0.y = p0.z = p0.w = 0.f;
                p1.x = p1.y = p1.z = p1.w = 0.f;
            }
            float4 m0 = *(const float4*)(mix + k0 + ac);
            float4 m1 = *(const float4*)(mix + k0 + ac + 4);
            const float* cf0 = (const float*)&c0; const float* cf1 = (const float*)&c1;
            const float* pf0 = (const float*)&p0; const float* pf1 = (const float*)&p1;
            const float* mf0 = (const float*)&m0; const float* mf1 = (const float*)&m1;
            ushort4 u0, u1;
            unsigned short* up0 = (unsigned short*)&u0;
            unsigned short* up1 = (unsigned short*)&u1;
#pragma unroll
            for (int j = 0; j < 4; ++j) {
                up0[j] = f2bf(cf0[j] + (pf0[j] - cf0[j]) * mf0[j]);
                up1[j] = f2bf(cf1[j] + (pf1[j] - cf1[j]) * mf1[j]);
            }
            *(ushort4*)&As[ar][ac] = u0;
            *(ushort4*)&As[ar][ac + 4] = u1;
        }
        {
            int br = tid >> 2, bc = (tid & 3) * 8;
            *(uint4*)&Bs[br][bc] = *(const uint4*)(WT + (size_t)(col0 + br) * Cc + k0 + bc);
        }
        __syncthreads();
        bf16x8 af, bff[4];
        af = *(const bf16x8*)&As[wave * 16 + lr][lk * 8];
#pragma unroll
        for (int n = 0; n < 4; ++n)
            bff[n] = *(const bf16x8*)&Bs[n * 16 + lr][lk * 8];
#pragma unroll
        for (int n = 0; n < 4; ++n)
            acc[n] = __builtin_amdgcn_mfma_f32_16x16x32_bf16(af, bff[n], acc[n], 0, 0, 0);
        __syncthreads();
    }

#pragma unroll
    for (int n = 0; n < 4; ++n) {
        int col = col0 + n * 16 + lr;
#pragma unroll
        for (int r = 0; r < 4; ++r) {
            int row = row0 + wave * 16 + lk * 4 + r;
            float v = acc[n][r];
            if (epi == 1) v = tanhf(v);
            else if (epi == 2) v = sigf(v);
            out[(size_t)row * N + col] = f2bf(v);
        }
    }
}

// ---------------------------------------------------------------------------
// stage-2 low-rank MFMA, fused. z0: wdb=decay -> bf16; z1: ab=sig -> f32;
// z2: gb -> bf16.
// ---------------------------------------------------------------------------
__global__ __launch_bounds__(256) void stage2_fused(
    const unsigned short* __restrict__ hw, const unsigned short* __restrict__ ha,
    const unsigned short* __restrict__ hg,
    const unsigned short* __restrict__ w2t, const unsigned short* __restrict__ a2t,
    const unsigned short* __restrict__ g2t,
    unsigned short* __restrict__ wdbh, float* __restrict__ abf,
    unsigned short* __restrict__ gb,
    const float* __restrict__ w0, const float* __restrict__ a0)
{
    const int z = blockIdx.z;
    const unsigned short* A  = z == 0 ? hw : z == 1 ? ha : hg;
    const unsigned short* WT = z == 0 ? w2t : z == 1 ? a2t : g2t;
    const float* bias = z == 0 ? w0 : z == 1 ? a0 : nullptr;
    const int K = (z == 2) ? 128 : 64;
    const int N = Cc;

    __shared__ __attribute__((aligned(16))) unsigned short As[128 * 32];
    __shared__ __attribute__((aligned(16))) unsigned short Bs[64 * 32];
    const int row0 = blockIdx.y * 128;
    const int col0 = blockIdx.x * 64;
    const int tid = threadIdx.x;
    const int wave = tid >> 6, lane = tid & 63;
    const int lr = lane & 15, lk = lane >> 4;

    f32x4 acc[2][4];
#pragma unroll
    for (int m = 0; m < 2; ++m)
#pragma unroll
        for (int n = 0; n < 4; ++n)
#pragma unroll
            for (int r = 0; r < 4; ++r) acc[m][n][r] = 0.f;

    const int lrow = lane >> 2;
    const int lcol8 = (lane & 3) * 8;

    for (int k0 = 0; k0 < K; k0 += 32) {
#pragma unroll
        for (int e = 0; e < 2; ++e) {
            int cib = wave * 128 + e * 64;
            int row = (cib >> 2) + lrow;
            gload16(A + (size_t)(row0 + row) * K + k0 + lcol8, &As[cib * 8]);
        }
        {
            int cib = wave * 64;
            int row = (cib >> 2) + lrow;
            gload16(WT + (size_t)(col0 + row) * K + k0 + lcol8, &Bs[cib * 8]);
        }
        __syncthreads();
        bf16x8 af[2], bff[4];
#pragma unroll
        for (int m = 0; m < 2; ++m)
            af[m] = *(const bf16x8*)&As[(wave * 32 + m * 16 + lr) * 32 + lk * 8];
#pragma unroll
        for (int n = 0; n < 4; ++n)
            bff[n] = *(const bf16x8*)&Bs[(n * 16 + lr) * 32 + lk * 8];
#pragma unroll
        for (int m = 0; m < 2; ++m)
#pragma unroll
            for (int n = 0; n < 4; ++n)
                acc[m][n] = __builtin_amdgcn_mfma_f32_16x16x32_bf16(af[m], bff[n], acc[m][n], 0, 0, 0);
        __syncthreads();
    }

#pragma unroll
    for (int m = 0; m < 2; ++m)
#pragma unroll
        for (int n = 0; n < 4; ++n) {
            int col = col0 + n * 16 + lr;
#pragma unroll
            for (int r = 0; r < 4; ++r) {
                int row = row0 + wave * 32 + m * 16 + lk * 4 + r;
                float v = acc[m][n][r];
                if (bias) v += bias[col];
                if (z == 0) {
                    v = expf(-0.60653065971263342f * sigf(v));
                    wdbh[(size_t)row * N + col] = f2bf(v);
                } else if (z == 1) {
                    abf[(size_t)row * N + col] = sigf(v);
                } else {
                    gb[(size_t)row * N + col] = f2bf(v);
                }
            }
        }
}

// ---------------------------------------------------------------------------
// WKV chunked, phase 1 (aa/bb inline during staging; k_final inline in C-task;
// A_l dumped to global bf16). k_k/k_a indexed by ABSOLUTE channel h*HSs+off.
// ---------------------------------------------------------------------------
__global__ __launch_bounds__(256, 1) void wkv_chunk1(
    const unsigned short* __restrict__ rbh, const unsigned short* __restrict__ wdbh,
    const unsigned short* __restrict__ kraw, const float* __restrict__ abf,
    const float* __restrict__ k_k, const float* __restrict__ k_a,
    unsigned short* __restrict__ TLt,  // [blk][j=64][p=64]
    unsigned short* __restrict__ Rho,  // [blk][t=32][p=64]
    unsigned short* __restrict__ ZLt,  // [blk][j=64][s=32]
    unsigned short* __restrict__ Alh)  // [blk][t=32][s=32]
{
    __shared__ float st[CL * STRD];    // arrays: 0=aa 1=wd 2=bb 3=r
    __shared__ float A_l[CL][CL + 1];
    const int blk = blockIdx.x;
    const int bh = blk >> 5;
    const int c  = blk & (NCH - 1);
    const int b = bh >> 4, h = bh & 15;
    const size_t base = (size_t)b * Tt * Cc + h * HSs + (size_t)c * CL * Cc;
    const int tid = threadIdx.x;

    // ---- stage: wd,r direct; aa,bb computed (head-norm via 8-lane reduce) ----
    {
        const int s = tid >> 3, j8 = (tid & 7) * 8;
        const size_t go = base + (size_t)s * Cc + j8;
        {
            uint4 u = *(const uint4*)(wdbh + go);
            const unsigned int* q = (const unsigned int*)&u;
            float4 f0, f1;
            f0.x = __uint_as_float(q[0] << 16); f0.y = __uint_as_float(q[0] & 0xFFFF0000u);
            f0.z = __uint_as_float(q[1] << 16); f0.w = __uint_as_float(q[1] & 0xFFFF0000u);
            f1.x = __uint_as_float(q[2] << 16); f1.y = __uint_as_float(q[2] & 0xFFFF0000u);
            f1.z = __uint_as_float(q[3] << 16); f1.w = __uint_as_float(q[3] & 0xFFFF0000u);
            *(float4*)&st[s * STRD + 1 * 64 + j8] = f0;
            *(float4*)&st[s * STRD + 1 * 64 + j8 + 4] = f1;
        }
        {
            uint4 u = *(const uint4*)(rbh + go);
            const unsigned int* q = (const unsigned int*)&u;
            float4 f0, f1;
            f0.x = __uint_as_float(q[0] << 16); f0.y = __uint_as_float(q[0] & 0xFFFF0000u);
            f0.z = __uint_as_float(q[1] << 16); f0.w = __uint_as_float(q[1] & 0xFFFF0000u);
            f1.x = __uint_as_float(q[2] << 16); f1.y = __uint_as_float(q[2] & 0xFFFF0000u);
            f1.z = __uint_as_float(q[3] << 16); f1.w = __uint_as_float(q[3] & 0xFFFF0000u);
            *(float4*)&st[s * STRD + 3 * 64 + j8] = f0;
            *(float4*)&st[s * STRD + 3 * 64 + j8 + 4] = f1;
        }
        float kr[8];
        {
            uint4 u = *(const uint4*)(kraw + go);
            UNPK8(kr, u, 0);
        }
        float4 av0 = *(const float4*)(abf + go);
        float4 av1 = *(const float4*)(abf + go + 4);
        const float* avp0 = (const float*)&av0;
        const float* avp1 = (const float*)&av1;
        const int ch0 = h * HSs + j8;          // ABSOLUTE channel
        float4 kk0 = *(const float4*)(k_k + ch0);
        float4 kk1 = *(const float4*)(k_k + ch0 + 4);
        const float* kkw = (const float*)&kk0;
        const float* kkw1 = (const float*)&kk1;
        float kkv[8];
#pragma unroll
        for (int j = 0; j < 4; ++j) {
            kkv[j] = kr[j] * kkw[j];
            kkv[4 + j] = kr[4 + j] * kkw1[j];
        }
        float ssq = 0.f;
#pragma unroll
        for (int j = 0; j < 8; ++j) ssq = fmaf(kkv[j], kkv[j], ssq);
        ssq = dpp_add_xor1(ssq);
        ssq = dpp_add_xor2(ssq);
        ssq += __shfl_xor(ssq, 4);
        float inv = 1.f / fmaxf(sqrtf(ssq), 1e-12f);
        float4 aa0, aa1, bb0, bb1;
        float* aap = (float*)&aa0; float* bbp = (float*)&bb0;
#pragma unroll
        for (int j = 0; j < 4; ++j) {
            float kkn = kkv[j] * inv;
            aap[j] = -kkn;
            bbp[j] = kkn * avp0[j];
        }
        float* aq = (float*)&aa1; float* bq = (float*)&bb1;
#pragma unroll
        for (int j = 0; j < 4; ++j) {
            float kkn = kkv[4 + j] * inv;
            aq[j] = -kkn;
            bq[j] = kkn * avp1[j];
        }
        *(float4*)&st[s * STRD + 0 * 64 + j8] = aa0;
        *(float4*)&st[s * STRD + 0 * 64 + j8 + 4] = aa1;
        *(float4*)&st[s * STRD + 2 * 64 + j8] = bb0;
        *(float4*)&st[s * STRD + 2 * 64 + j8 + 4] = bb1;
    }
    __syncthreads();

    const int wv = tid >> 6, lane = tid & 63;
    if (wv < 2) {
        // ---- B-task: 2 rows x 16 cols per thread, 2 waves = 64 rows ----
        const int idx = wv * 64 + lane;
        const int rq = idx >> 2, jc = idx & 3;
        const int i0 = rq * 2, j0 = jc * 16;
        float T[2][16];
#pragma unroll
        for (int rr = 0; rr < 2; ++rr)
#pragma unroll
            for (int cc = 0; cc < 16; ++cc)
                T[rr][cc] = (i0 + rr == j0 + cc) ? 1.f : 0.f;
        const size_t rhob = (size_t)blk * (CL * 64);

        for (int t = 0; t < CL; ++t) {
            const float* sp = st + t * STRD;
            float a[16], w[16], bv[16], r[16];
#pragma unroll
            for (int q = 0; q < 4; ++q) {
                *(float4*)&a[q * 4]  = *(const float4*)(sp + 0 * 64 + j0 + q * 4);
                *(float4*)&w[q * 4]  = *(const float4*)(sp + 1 * 64 + j0 + q * 4);
                *(float4*)&bv[q * 4] = *(const float4*)(sp + 2 * 64 + j0 + q * 4);
                *(float4*)&r[q * 4]  = *(const float4*)(sp + 3 * 64 + j0 + q * 4);
            }
            float ta[2];
#pragma unroll
            for (int rr = 0; rr < 2; ++rr) {
                float q0 = T[rr][0] * a[0], q1 = T[rr][4] * a[4];
                float q2 = T[rr][8] * a[8], q3 = T[rr][12] * a[12];
#pragma unroll
                for (int e = 1; e < 4; ++e) {
                    q0 = fmaf(T[rr][e], a[e], q0);
                    q1 = fmaf(T[rr][4 + e], a[4 + e], q1);
                    q2 = fmaf(T[rr][8 + e], a[8 + e], q2);
                    q3 = fmaf(T[rr][12 + e], a[12 + e], q3);
                }
                ta[rr] = (q0 + q1) + (q2 + q3);
            }
#pragma unroll
            for (int rr = 0; rr < 2; ++rr) {
                ta[rr] = dpp_add_xor1(ta[rr]);
                ta[rr] = dpp_add_xor2(ta[rr]);
            }
            float rp[2];
#pragma unroll
            for (int rr = 0; rr < 2; ++rr) {
                float q0 = 0.f, q1 = 0.f, q2 = 0.f, q3 = 0.f;
#pragma unroll
                for (int e = 0; e < 4; ++e) {
                    T[rr][e]      = fmaf(T[rr][e],      w[e],      ta[rr] * bv[e]);
                    T[rr][4 + e]  = fmaf(T[rr][4 + e],  w[4 + e],  ta[rr] * bv[4 + e]);
                    T[rr][8 + e]  = fmaf(T[rr][8 + e],  w[8 + e],  ta[rr] * bv[8 + e]);
                    T[rr][12 + e] = fmaf(T[rr][12 + e], w[12 + e], ta[rr] * bv[12 + e]);
                    q0 = fmaf(T[rr][e], r[e], q0);
                    q1 = fmaf(T[rr][4 + e], r[4 + e], q1);
                    q2 = fmaf(T[rr][8 + e], r[8 + e], q2);
                    q3 = fmaf(T[rr][12 + e], r[12 + e], q3);
                }
                rp[rr] = (q0 + q1) + (q2 + q3);
            }
#pragma unroll
            for (int rr = 0; rr < 2; ++rr) {
                rp[rr] = dpp_add_xor1(rp[rr]);
                rp[rr] = dpp_add_xor2(rp[rr]);
            }
            if (jc == 0) {
                ushort2 o2;
                o2.x = f2bf(rp[0]); o2.y = f2bf(rp[1]);
                *(ushort2*)(Rho + rhob + t * 64 + i0) = o2;
            }
        }
        const size_t tlb = (size_t)blk * 4096;
#pragma unroll
        for (int cc = 0; cc < 16; ++cc) {
            ushort2 o2;
            o2.x = f2bf(T[0][cc]); o2.y = f2bf(T[1][cc]);
            *(ushort2*)(TLt + tlb + (size_t)(j0 + cc) * 64 + i0) = o2;
        }
    } else {
        // ---- C-task: 1 s x 16 cols per thread; k_final computed inline ----
        const int idx2 = (wv - 2) * 64 + lane;
        const int s = idx2 >> 2, q4 = idx2 & 3;
        const int j0 = q4 * 16;
        float kreg[16];
        {
            float kr[16];
            uint4 u0 = *(const uint4*)(kraw + base + (size_t)s * Cc + j0);
            uint4 u1 = *(const uint4*)(kraw + base + (size_t)s * Cc + j0 + 8);
            UNPK8(kr, u0, 0); UNPK8(kr, u1, 8);
#pragma unroll
            for (int q = 0; q < 4; ++q) {
                float4 av4 = *(const float4*)(abf + base + (size_t)s * Cc + j0 + q * 4);
                float4 ka4 = *(const float4*)(k_a + h * HSs + j0 + q * 4);   // ABSOLUTE
                const float* avp = (const float*)&av4;
                const float* kap = (const float*)&ka4;
#pragma unroll
                for (int e = 0; e < 4; ++e) {
                    int u = q * 4 + e;
                    kreg[u] = kr[u] * (1.f + (avp[e] - 1.f) * kap[e]);
                }
            }
        }
        float z[16];
#pragma unroll
        for (int u = 0; u < 16; ++u) z[u] = 0.f;

        for (int t = 0; t < CL; ++t) {
            const float* sp = st + t * STRD;
            float a[16], w[16], bv[16], r[16];
#pragma unroll
            for (int q = 0; q < 4; ++q) {
                *(float4*)&a[q * 4]  = *(const float4*)(sp + 0 * 64 + j0 + q * 4);
                *(float4*)&w[q * 4]  = *(const float4*)(sp + 1 * 64 + j0 + q * 4);
                *(float4*)&bv[q * 4] = *(const float4*)(sp + 2 * 64 + j0 + q * 4);
                *(float4*)&r[q * 4]  = *(const float4*)(sp + 3 * 64 + j0 + q * 4);
            }
            float q0 = z[0] * a[0], q1 = z[4] * a[4];
            float q2 = z[8] * a[8], q3 = z[12] * a[12];
#pragma unroll
            for (int e = 1; e < 4; ++e) {
                q0 = fmaf(z[e], a[e], q0);
                q1 = fmaf(z[4 + e], a[4 + e], q1);
                q2 = fmaf(z[8 + e], a[8 + e], q2);
                q3 = fmaf(z[12 + e], a[12 + e], q3);
            }
            float za = (q0 + q1) + (q2 + q3);
            za = dpp_add_xor1(za);
            za = dpp_add_xor2(za);
#pragma unroll
            for (int u = 0; u < 16; ++u)
                z[u] = fmaf(z[u], w[u], za * bv[u]);
            if (s == t) {
#pragma unroll
                for (int u = 0; u < 16; ++u) z[u] = kreg[u];
            }
            float p0 = z[0] * r[0], p1 = z[4] * r[4];
            float p2 = z[8] * r[8], p3 = z[12] * r[12];
#pragma unroll
            for (int e = 1; e < 4; ++e) {
                p0 = fmaf(z[e], r[e], p0);
                p1 = fmaf(z[4 + e], r[4 + e], p1);
                p2 = fmaf(z[8 + e], r[8 + e], p2);
                p3 = fmaf(z[12 + e], r[12 + e], p3);
            }
            float al = (p0 + p1) + (p2 + p3);
            al = dpp_add_xor1(al);
            al = dpp_add_xor2(al);
            if (q4 == 0) A_l[t][s] = al;
        }
        const size_t zlb = (size_t)blk * (CL * 64);
#pragma unroll
        for (int u = 0; u < 16; ++u)
            ZLt[zlb + (size_t)(j0 + u) * 32 + s] = f2bf(z[u]);
    }
    __syncthreads();

    // ---- dump A_l -> Alh (bf16, [t][s], coalesced) ----
    if (tid < 128) {
        const int t = tid >> 2, s8 = (tid & 3) * 8;
        ushort4 o0, o1;
        unsigned short* p0 = (unsigned short*)&o0;
        unsigned short* p1 = (unsigned short*)&o1;
#pragma unroll
        for (int e = 0; e < 4; ++e) {
            p0[e] = f2bf(A_l[t][s8 + e]);
            p1[e] = f2bf(A_l[t][s8 + 4 + e]);
        }
        unsigned short* dst = Alh + (size_t)blk * 1024 + t * 32 + s8;
        *(ushort4*)dst = o0;
        *(ushort4*)(dst + 4) = o1;
    }
}

// ---------------------------------------------------------------------------
// WKV chunked, phase 2 — MFMA; y = S0·rho + V^T·A_l computed in-register and
// IMMEDIATELY GroupNorm'd + bonus + gated -> zb (bf16). y never materialized.
// ---------------------------------------------------------------------------
__global__ __launch_bounds__(256, 1) void wkv_chunk2(
    const unsigned short* __restrict__ vbh, const unsigned short* __restrict__ TLt,
    const unsigned short* __restrict__ Rho, const unsigned short* __restrict__ ZLt,
    const unsigned short* __restrict__ Alh,
    const unsigned short* __restrict__ rbh, const unsigned short* __restrict__ kraw,
    const float* __restrict__ abf, const unsigned short* __restrict__ gb,
    const float* __restrict__ r_k, const float* __restrict__ k_a,
    const float* __restrict__ ln_w, const float* __restrict__ ln_b,
    unsigned short* __restrict__ zb)
{
    __shared__ unsigned short Sl[64 * 72];
    __shared__ unsigned short Ttl[64 * 72];
    __shared__ unsigned short Ztl[64 * 40];
    __shared__ unsigned short Rl[32 * 72];
    __shared__ unsigned short Vtl[64 * 40];
    __shared__ unsigned short All[32 * 40];
    __shared__ float Yl[32 * 68];
    const int bh = blockIdx.x;
    const int h = bh & 15;
    const size_t vbase = (size_t)(bh >> 4) * Tt * Cc + h * HSs;
    const int tid = threadIdx.x;
    const int wv = tid >> 6, lane = tid & 63;
    const int lr = lane & 15, lk = lane >> 4;
    const int i0w = wv * 16;

    f32x4 S[4];
#pragma unroll
    for (int n = 0; n < 4; ++n)
#pragma unroll
        for (int r = 0; r < 4; ++r) S[n][r] = 0.f;

    // GN pass thread mapping + loop-invariant per-channel params
    const int gt = tid >> 3;            // t within chunk 0..31
    const int gi = (tid & 7) * 8;       // i offset 0..56
    const int chb = h * HSs + gi;       // absolute channel base
    float ka8[8], rk8[8], lnw8[8], lnb8[8];
    *(float4*)&ka8[0] = *(const float4*)(k_a + chb);
    *(float4*)&ka8[4] = *(const float4*)(k_a + chb + 4);
    *(float4*)&rk8[0] = *(const float4*)(r_k + chb);
    *(float4*)&rk8[4] = *(const float4*)(r_k + chb + 4);
    *(float4*)&lnw8[0] = *(const float4*)(ln_w + chb);
    *(float4*)&lnw8[4] = *(const float4*)(ln_w + chb + 4);
    *(float4*)&lnb8[0] = *(const float4*)(ln_b + chb);
    *(float4*)&lnb8[4] = *(const float4*)(ln_b + chb + 4);

    uint4 pT0, pT1, pZ, pR, pAl, pVu;
    const int vs = tid >> 3, vi0 = (tid & 7) * 8;

#define C2_LOAD(c_) do { \
    size_t cb_ = (size_t)(bh * NCH + (c_)); \
    const uint4* tp_ = (const uint4*)(TLt + cb_ * 4096); \
    pT0 = tp_[tid * 2]; pT1 = tp_[tid * 2 + 1]; \
    pZ = ((const uint4*)(ZLt + cb_ * 2048))[tid]; \
    pR = ((const uint4*)(Rho + cb_ * 2048))[tid]; \
    if (tid < 128) pAl = ((const uint4*)(Alh + cb_ * 1024))[tid]; \
    pVu = *(const uint4*)(vbh + vbase + (size_t)((c_) * CL + vs) * Cc + vi0); \
} while (0)

#define C2_STORE() do { \
    *(uint4*)&Ttl[(tid >> 2) * 72 + (tid & 3) * 16] = pT0; \
    *(uint4*)&Ttl[(tid >> 2) * 72 + (tid & 3) * 16 + 8] = pT1; \
    *(uint4*)&Ztl[(tid >> 2) * 40 + (tid & 3) * 8] = pZ; \
    *(uint4*)&Rl[(tid >> 3) * 72 + (tid & 7) * 8] = pR; \
    if (tid < 128) *(uint4*)&All[(tid >> 2) * 40 + (tid & 3) * 8] = pAl; \
    const unsigned short* pvu_ = (const unsigned short*)&pVu; \
    Vtl[(vi0 + 0) * 40 + vs] = pvu_[0]; \
    Vtl[(vi0 + 1) * 40 + vs] = pvu_[1]; \
    Vtl[(vi0 + 2) * 40 + vs] = pvu_[2]; \
    Vtl[(vi0 + 3) * 40 + vs] = pvu_[3]; \
    Vtl[(vi0 + 4) * 40 + vs] = pvu_[4]; \
    Vtl[(vi0 + 5) * 40 + vs] = pvu_[5]; \
    Vtl[(vi0 + 6) * 40 + vs] = pvu_[6]; \
    Vtl[(vi0 + 7) * 40 + vs] = pvu_[7]; \
} while (0)

    C2_LOAD(0);
    for (int c = 0; c < NCH; ++c) {
        __syncthreads();   // prior GN pass (Yl reads) + MFMAs done; LDS writable
#pragma unroll
        for (int n = 0; n < 4; ++n) {
#pragma unroll
            for (int r = 0; r < 4; ++r)
                Sl[(i0w + lk * 4 + r) * 72 + n * 16 + lr] = f2bf(S[n][r]);
        }
        C2_STORE();
        if (c + 1 < NCH) C2_LOAD(c + 1);
        __syncthreads();

        bf16x8 sA0 = *(const bf16x8*)&Sl[(i0w + lr) * 72 + lk * 8];
        bf16x8 sA1 = *(const bf16x8*)&Sl[(i0w + lr) * 72 + 32 + lk * 8];
        bf16x8 vA = *(const bf16x8*)&Vtl[(i0w + lr) * 40 + lk * 8];

        // y[t][i] -> Yl (LDS), never to global
#pragma unroll
        for (int nt = 0; nt < 2; ++nt) {
            int t = nt * 16 + lr;
            f32x4 yc = { 0.f, 0.f, 0.f, 0.f };
            bf16x8 b0 = *(const bf16x8*)&Rl[t * 72 + lk * 8];
            bf16x8 b1 = *(const bf16x8*)&Rl[t * 72 + 32 + lk * 8];
            bf16x8 al8 = *(const bf16x8*)&All[t * 40 + lk * 8];
            yc = __builtin_amdgcn_mfma_f32_16x16x32_bf16(sA0, b0, yc, 0, 0, 0);
            yc = __builtin_amdgcn_mfma_f32_16x16x32_bf16(sA1, b1, yc, 0, 0, 0);
            yc = __builtin_amdgcn_mfma_f32_16x16x32_bf16(vA, al8, yc, 0, 0, 0);
            *(float4*)&Yl[t * 68 + i0w + lk * 4] = *(float4*)&yc;
        }

        // S <- S·T + V^T·Z
#pragma unroll
        for (int n = 0; n < 4; ++n) {
            int j = n * 16 + lr;
            bf16x8 t0 = *(const bf16x8*)&Ttl[j * 72 + lk * 8];
            bf16x8 t1 = *(const bf16x8*)&Ttl[j * 72 + 32 + lk * 8];
            bf16x8 z0 = *(const bf16x8*)&Ztl[j * 40 + lk * 8];
            f32x4 acc = { 0.f, 0.f, 0.f, 0.f };
            acc = __builtin_amdgcn_mfma_f32_16x16x32_bf16(sA0, t0, acc, 0, 0, 0);
            acc = __builtin_amdgcn_mfma_f32_16x16x32_bf16(sA1, t1, acc, 0, 0, 0);
            acc = __builtin_amdgcn_mfma_f32_16x16x32_bf16(vA, z0, acc, 0, 0, 0);
            S[n] = acc;
        }

        __syncthreads();   // Yl complete

        // ---- fused GroupNorm + bonus + gate -> zb ----
        {
            const size_t grow = vbase + (size_t)(c * CL + gt) * Cc + gi;
            float y8[8];
            *(float4*)&y8[0] = *(const float4*)&Yl[gt * 68 + gi];
            *(float4*)&y8[4] = *(const float4*)&Yl[gt * 68 + gi + 4];
            float r8[8], k8[8], g8[8], v8[8];
            uint4 ur = *(const uint4*)(rbh + grow);  UNPK8(r8, ur, 0);
            uint4 uk = *(const uint4*)(kraw + grow); UNPK8(k8, uk, 0);
            uint4 ug = *(const uint4*)(gb + grow);   UNPK8(g8, ug, 0);
            uint4 uv = *(const uint4*)(vbh + grow);  UNPK8(v8, uv, 0);
            float a8[8];
            *(float4*)&a8[0] = *(const float4*)(abf + grow);
            *(float4*)&a8[4] = *(const float4*)(abf + grow + 4);

            float sum = 0.f, ssq = 0.f, dot = 0.f;
            float kf8[8];
#pragma unroll
            for (int j = 0; j < 8; ++j) {
                kf8[j] = k8[j] * (1.f + (a8[j] - 1.f) * ka8[j]);
                sum += y8[j];
                ssq = fmaf(y8[j], y8[j], ssq);
                dot = fmaf(r8[j] * kf8[j], rk8[j], dot);
            }
            sum = dpp_add_xor1(sum); sum = dpp_add_xor2(sum); sum += __shfl_xor(sum, 4);
            ssq = dpp_add_xor1(ssq); ssq = dpp_add_xor2(ssq); ssq += __shfl_xor(ssq, 4);
            dot = dpp_add_xor1(dot); dot = dpp_add_xor2(dot); dot += __shfl_xor(dot, 4);
            const float mu = sum * (1.f / 64.f);
            const float var = ssq * (1.f / 64.f) - mu * mu;
            const float inv = rsqrtf(var + 0.00064f);

            ushort4 z0o, z1o;
            unsigned short* zp0 = (unsigned short*)&z0o;
            unsigned short* zp1 = (unsigned short*)&z1o;
#pragma unroll
            for (int j = 0; j < 4; ++j) {
                float yg0 = (y8[j] - mu) * inv * lnw8[j] + lnb8[j] + dot * v8[j];
                float yg1 = (y8[4 + j] - mu) * inv * lnw8[4 + j] + lnb8[4 + j] + dot * v8[4 + j];
                zp0[j] = f2bf(yg0 * g8[j]);
                zp1[j] = f2bf(yg1 * g8[4 + j]);
            }
            *(ushort4*)(zb + grow) = z0o;
            *(ushort4*)(zb + grow + 4) = z1o;
        }
    }
#undef C2_LOAD
#undef C2_STORE
}

// ---------------------------------------------------------------------------

extern "C" void kernel_launch(void* const* d_in, const int* in_sizes, int n_in,
                              void* d_out, int out_size, void* d_ws, size_t ws_size,
                              hipStream_t stream)
{
    const float* x   = (const float*)d_in[0];
    const float* x_r = (const float*)d_in[1];
    const float* x_w = (const float*)d_in[2];
    const float* x_k = (const float*)d_in[3];
    const float* x_v = (const float*)d_in[4];
    const float* x_a = (const float*)d_in[5];
    const float* x_g = (const float*)d_in[6];
    const float* w0  = (const float*)d_in[7];
    const float* w1  = (const float*)d_in[8];
    const float* w2  = (const float*)d_in[9];
    const float* a0  = (const float*)d_in[10];
    const float* a1  = (const float*)d_in[11];
    const float* a2  = (const float*)d_in[12];
    // v0,v1,v2 (13..15): forward no-op on first-layer call
    const float* g1  = (const float*)d_in[16];
    const float* g2  = (const float*)d_in[17];
    const float* k_k = (const float*)d_in[18];
    const float* k_a = (const float*)d_in[19];
    const float* r_k = (const float*)d_in[20];
    const float* Wr  = (const float*)d_in[21];
    const float* Wk  = (const float*)d_in[22];
    const float* Wv  = (const float*)d_in[23];
    const float* Wo  = (const float*)d_in[24];
    const float* ln_w = (const float*)d_in[25];
    const float* ln_b = (const float*)d_in[26];

    float* ws = (float*)d_ws;
    const size_t S = (size_t)Bsz * Tt * Cc;       // 4,194,304 elements
    const int M = Bsz * Tt;                        // 4096

    // slot0: rbh (bf16, 8MB) + zb (bf16, 8MB)
    unsigned short* rbh = (unsigned short*)(ws + 0 * S);
    unsigned short* zb  = (unsigned short*)ws + S;
    // slot1: wdbh + gb
    unsigned short* wdbh = (unsigned short*)(ws + 1 * S);
    unsigned short* gb  = (unsigned short*)(ws + 1 * S) + S;
    // slot2: kbh (kraw) + vbh
    unsigned short* kbh = (unsigned short*)(ws + 2 * S);
    unsigned short* vbh = (unsigned short*)(ws + 2 * S) + S;
    // slot3: abf (fp32, 16MB)
    float* abf = ws + 3 * S;
    // slot5: xr + xk -> Rho + ZLt after gemm_rkv
    unsigned short* xr = (unsigned short*)(ws + 5 * S);
    unsigned short* xk = (unsigned short*)(ws + 5 * S) + S;
    unsigned short* Rho = xr;
    unsigned short* ZLt = xk;
    // slot6: xv (8MB) + h-buffers + small weight transposes
    unsigned short* xv = (unsigned short*)(ws + 6 * S);
    unsigned short* hw = xv + S;
    unsigned short* ha = hw + 262144;
    unsigned short* hg = ha + 262144;
    unsigned short* w1t = hg + 524288;
    unsigned short* a1t = w1t + 65536;
    unsigned short* g1t = a1t + 65536;
    unsigned short* w2t = g1t + 131072;
    unsigned short* a2t = w2t + 65536;
    unsigned short* g2t = a2t + 65536;
    // slot7: WrT/WkT/WvT/WoT (2MB each) + Alh (4MB)
    unsigned short* WrT = (unsigned short*)(ws + 7 * S);
    unsigned short* WkT = WrT + 1048576;
    unsigned short* WvT = WkT + 1048576;
    unsigned short* WoT = WvT + 1048576;
    unsigned short* Alh = WoT + 1048576;
    // slot8: TLt (16MB)
    unsigned short* TLt = (unsigned short*)(ws + 8 * S);

    dim3 blk(256);

    // 1. prep: mixcast + weight transposes
    prep_all<<<dim3(4096 + 1024 + 128), blk, 0, stream>>>(
        x, x_r, x_k, x_v, Wr, Wk, Wv, Wo, w1, a1, g1, w2, a2, g2,
        xr, xk, xv, WrT, WkT, WvT, WoT, w1t, a1t, g1t, w2t, a2t, g2t);

    // 2. stage-1 low-rank (BM=64: 256 blocks fills the chip)
    lowrank1_fused<<<dim3(4, 64), blk, 0, stream>>>(x, x_w, x_a, x_g, w1t, a1t, g1t, hw, ha, hg);

    // 3. r/k/v projections (all bf16 out; k stays raw), XCD-swizzled
    gemm_rkv<<<dim3(8, 32, 3), blk, 0, stream>>>(xr, xk, xv, WrT, WkT, WvT, rbh, kbh, vbh);

    // 4. stage-2 low-rank (wd/g bf16, ab fp32)
    stage2_fused<<<dim3(16, 32, 3), blk, 0, stream>>>(hw, ha, hg, w2t, a2t, g2t, wdbh, abf, gb, w0, a0);

    // 5-6. chunked recurrence; chunk2 fuses GN+bonus+gate -> zb
    wkv_chunk1<<<dim3(64 * NCH), dim3(256), 0, stream>>>(rbh, wdbh, kbh, abf, k_k, k_a, TLt, Rho, ZLt, Alh);
    wkv_chunk2<<<dim3(64), blk, 0, stream>>>(vbh, TLt, Rho, ZLt, Alh,
                                             rbh, kbh, abf, gb, r_k, k_a, ln_w, ln_b, zb);

    // 7. output projection (XCD-swizzled)
    gemm_bf16<<<dim3(8, 32), blk, 0, stream>>>(zb, WoT, (float*)d_out, M, Cc, Cc);
}

// Round 22
// 223.783 us; speedup vs baseline: 1.0691x; 1.0691x over previous
//
#include <hip/hip_runtime.h>
#include <math.h>

#define Bsz 4
#define Tt  1024
#define Cc  1024
#define Hh  16
#define HSs 64
#define CL  32            // wkv chunk length
#define NCH (Tt / CL)     // 32 chunks
#define STRD 260          // fp32 step stride (4 arrays x 64 + 4 pad)

typedef __attribute__((ext_vector_type(8))) short bf16x8;
typedef __attribute__((ext_vector_type(4))) float f32x4;

__device__ __forceinline__ float sigf(float x) { return 1.f / (1.f + expf(-x)); }

__device__ __forceinline__ unsigned short f2bf(float f) {
    unsigned int u = __float_as_uint(f);
    u = u + 0x7fffu + ((u >> 16) & 1u);   // RNE
    return (unsigned short)(u >> 16);
}
__device__ __forceinline__ float bf2f(unsigned short u) {
    return __uint_as_float(((unsigned int)u) << 16);
}
__device__ __forceinline__ float dpp_add_xor1(float x) {
    int y = __builtin_amdgcn_mov_dpp(__float_as_int(x), 0xB1, 0xF, 0xF, true);
    return x + __int_as_float(y);
}
__device__ __forceinline__ float dpp_add_xor2(float x) {
    int y = __builtin_amdgcn_mov_dpp(__float_as_int(x), 0x4E, 0xF, 0xF, true);
    return x + __int_as_float(y);
}

// async global->LDS, 16B per lane; lds must be wave-uniform base
__device__ __forceinline__ void gload16(const void* g, void* l) {
    __builtin_amdgcn_global_load_lds(
        (const __attribute__((address_space(1))) unsigned int*)g,
        (__attribute__((address_space(3))) unsigned int*)l, 16, 0, 0);
}

// unpack 8 packed bf16 (uint4) into dst[off..off+7]
#define UNPK8(dst, u4, off) do { \
    const unsigned int* q_ = (const unsigned int*)&(u4); \
    _Pragma("unroll") \
    for (int e_ = 0; e_ < 4; ++e_) { \
        (dst)[(off) + 2 * e_]     = __uint_as_float(q_[e_] << 16); \
        (dst)[(off) + 2 * e_ + 1] = __uint_as_float(q_[e_] & 0xFFFF0000u); \
    } \
} while (0)

// ---------------------------------------------------------------------------
// 64x64 transpose+cast helper
// ---------------------------------------------------------------------------
__device__ __forceinline__ void tcast64(
    const float* __restrict__ W, unsigned short* __restrict__ WT,
    int K, int N, int n0, int k0, int tid, unsigned short tile[64][68])
{
    const int tr = tid >> 4, tc4 = (tid & 15) * 4;
#pragma unroll
    for (int s = 0; s < 4; ++s) {
        int kk = tr + s * 16;
        float4 w4 = *(const float4*)(W + (size_t)(k0 + kk) * N + n0 + tc4);
        tile[kk][tc4 + 0] = f2bf(w4.x);
        tile[kk][tc4 + 1] = f2bf(w4.y);
        tile[kk][tc4 + 2] = f2bf(w4.z);
        tile[kk][tc4 + 3] = f2bf(w4.w);
    }
    __syncthreads();
#pragma unroll
    for (int s = 0; s < 4; ++s) {
        int nn = tr + s * 16;
        ushort4 o4;
        o4.x = tile[tc4 + 0][nn];
        o4.y = tile[tc4 + 1][nn];
        o4.z = tile[tc4 + 2][nn];
        o4.w = tile[tc4 + 3][nn];
        *(ushort4*)(WT + (size_t)(n0 + nn) * K + k0 + tc4) = o4;
    }
}

// ---------------------------------------------------------------------------
// prep_all: mixcast (blocks 0..4095) + 10 weight transposes
// ---------------------------------------------------------------------------
__global__ __launch_bounds__(256) void prep_all(
    const float* __restrict__ x, const float* __restrict__ x_r,
    const float* __restrict__ x_k, const float* __restrict__ x_v,
    const float* __restrict__ Wr, const float* __restrict__ Wk,
    const float* __restrict__ Wv, const float* __restrict__ Wo,
    const float* __restrict__ w1, const float* __restrict__ a1,
    const float* __restrict__ g1, const float* __restrict__ w2,
    const float* __restrict__ a2, const float* __restrict__ g2,
    unsigned short* __restrict__ xr, unsigned short* __restrict__ xk,
    unsigned short* __restrict__ xvo,
    unsigned short* __restrict__ WrT, unsigned short* __restrict__ WkT,
    unsigned short* __restrict__ WvT, unsigned short* __restrict__ WoT,
    unsigned short* __restrict__ w1t, unsigned short* __restrict__ a1t,
    unsigned short* __restrict__ g1t, unsigned short* __restrict__ w2t,
    unsigned short* __restrict__ a2t, unsigned short* __restrict__ g2t)
{
    __shared__ unsigned short tile[64][68];
    const int tid = threadIdx.x;
    int bid = blockIdx.x;

    if (bid < 4096) {
        const int row = bid;
        const int c0 = tid * 4;
        const size_t o = (size_t)row * Cc;
        float4 xc = *(const float4*)(x + o + c0);
        float4 xp;
        if (row & (Tt - 1)) xp = *(const float4*)(x + o - Cc + c0);
        else { xp.x = xp.y = xp.z = xp.w = 0.f; }
        float4 mr = *(const float4*)(x_r + c0);
        float4 mk = *(const float4*)(x_k + c0);
        float4 mv = *(const float4*)(x_v + c0);
        const float* xcf = (const float*)&xc; const float* xpf = (const float*)&xp;
        const float* mrf = (const float*)&mr; const float* mkf = (const float*)&mk;
        const float* mvf = (const float*)&mv;
        ushort4 r4, k4, v4;
        unsigned short* rp = (unsigned short*)&r4;
        unsigned short* kp = (unsigned short*)&k4;
        unsigned short* vp = (unsigned short*)&v4;
#pragma unroll
        for (int j = 0; j < 4; ++j) {
            float xx = xpf[j] - xcf[j];
            rp[j] = f2bf(xcf[j] + xx * mrf[j]);
            kp[j] = f2bf(xcf[j] + xx * mkf[j]);
            vp[j] = f2bf(xcf[j] + xx * mvf[j]);
        }
        *(ushort4*)(xr + o + c0) = r4;
        *(ushort4*)(xk + o + c0) = k4;
        *(ushort4*)(xvo + o + c0) = v4;
        return;
    }
    bid -= 4096;
    if (bid < 1024) {
        int which = bid >> 8, id0 = bid & 255;
        const float* W = which == 0 ? Wr : which == 1 ? Wk : which == 2 ? Wv : Wo;
        unsigned short* WT = which == 0 ? WrT : which == 1 ? WkT : which == 2 ? WvT : WoT;
        tcast64(W, WT, Cc, Cc, (id0 & 15) * 64, (id0 >> 4) * 64, tid, tile);
        return;
    }
    bid -= 1024;
    if (bid < 16) { tcast64(w1, w1t, Cc, 64, 0, bid * 64, tid, tile); return; }
    bid -= 16;
    if (bid < 16) { tcast64(a1, a1t, Cc, 64, 0, bid * 64, tid, tile); return; }
    bid -= 16;
    if (bid < 32) { tcast64(g1, g1t, Cc, 128, (bid & 1) * 64, (bid >> 1) * 64, tid, tile); return; }
    bid -= 32;
    if (bid < 16) { tcast64(w2, w2t, 64, Cc, bid * 64, 0, tid, tile); return; }
    bid -= 16;
    if (bid < 16) { tcast64(a2, a2t, 64, Cc, bid * 64, 0, tid, tile); return; }
    bid -= 16;
    tcast64(g2, g2t, 128, Cc, (bid & 15) * 64, (bid >> 4) * 64, tid, tile);
}

// ---------------------------------------------------------------------------
// big bf16 MFMA GEMM, r/k/v fused (z). All outputs bf16. XCD-swizzled blockIdx.
// ---------------------------------------------------------------------------
__global__ __launch_bounds__(256) void gemm_rkv(
    const unsigned short* __restrict__ xr, const unsigned short* __restrict__ xk,
    const unsigned short* __restrict__ xv,
    const unsigned short* __restrict__ WrT, const unsigned short* __restrict__ WkT,
    const unsigned short* __restrict__ WvT,
    unsigned short* __restrict__ rbh, unsigned short* __restrict__ kbh,
    unsigned short* __restrict__ vbh)
{
    const int z = blockIdx.z;
    const unsigned short* A  = z == 0 ? xr : z == 1 ? xk : xv;
    const unsigned short* WT = z == 0 ? WrT : z == 1 ? WkT : WvT;
    unsigned short* outh = z == 0 ? rbh : z == 1 ? kbh : vbh;
    const int K = Cc, N = Cc;

    // XCD swizzle: 256 blocks/z, XCD k gets contiguous work-ids -> A-panel reuse
    const int bid = blockIdx.x + 8 * blockIdx.y;      // 0..255
    const int swz = (bid & 7) * 32 + (bid >> 3);
    const int row0 = (swz >> 3) * 128;
    const int col0 = (swz & 7) * 128;

    __shared__ __attribute__((aligned(16))) unsigned short As[128 * 32];
    __shared__ __attribute__((aligned(16))) unsigned short Bs[128 * 32];
    const int tid = threadIdx.x;
    const int wave = tid >> 6, lane = tid & 63;
    const int wr = wave >> 1, wc = wave & 1;
    const int lr = lane & 15, lk = lane >> 4;

    f32x4 acc[4][4];
#pragma unroll
    for (int m = 0; m < 4; ++m)
#pragma unroll
        for (int n = 0; n < 4; ++n)
#pragma unroll
            for (int r = 0; r < 4; ++r) acc[m][n][r] = 0.f;

    const int lrow = lane >> 2;
    const int lcol8 = (lane & 3) * 8;

    for (int k0 = 0; k0 < K; k0 += 32) {
#pragma unroll
        for (int e = 0; e < 2; ++e) {
            int cib = wave * 128 + e * 64;
            int row = (cib >> 2) + lrow;
            gload16(A  + (size_t)(row0 + row) * K + k0 + lcol8, &As[cib * 8]);
            gload16(WT + (size_t)(col0 + row) * K + k0 + lcol8, &Bs[cib * 8]);
        }
        __syncthreads();
        bf16x8 af[4], bff[4];
#pragma unroll
        for (int m = 0; m < 4; ++m)
            af[m] = *(const bf16x8*)&As[(wr * 64 + m * 16 + lr) * 32 + lk * 8];
#pragma unroll
        for (int n = 0; n < 4; ++n)
            bff[n] = *(const bf16x8*)&Bs[(wc * 64 + n * 16 + lr) * 32 + lk * 8];
#pragma unroll
        for (int m = 0; m < 4; ++m)
#pragma unroll
            for (int n = 0; n < 4; ++n)
                acc[m][n] = __builtin_amdgcn_mfma_f32_16x16x32_bf16(af[m], bff[n], acc[m][n], 0, 0, 0);
        __syncthreads();
    }

#pragma unroll
    for (int m = 0; m < 4; ++m)
#pragma unroll
        for (int n = 0; n < 4; ++n) {
            int col = col0 + wc * 64 + n * 16 + lr;
#pragma unroll
            for (int r = 0; r < 4; ++r) {
                int row = row0 + wr * 64 + m * 16 + lk * 4 + r;
                outh[(size_t)row * N + col] = f2bf(acc[m][n][r]);
            }
        }
}

// ---------------------------------------------------------------------------
// plain 128x128 bf16 GEMM (Wo projection), XCD-swizzled
// ---------------------------------------------------------------------------
__global__ __launch_bounds__(256) void gemm_bf16(
    const unsigned short* __restrict__ A, const unsigned short* __restrict__ WT,
    float* __restrict__ out, int M, int N, int K)
{
    __shared__ __attribute__((aligned(16))) unsigned short As[128 * 32];
    __shared__ __attribute__((aligned(16))) unsigned short Bs[128 * 32];
    const int bid = blockIdx.x + 8 * blockIdx.y;      // 0..255
    const int swz = (bid & 7) * 32 + (bid >> 3);
    const int row0 = (swz >> 3) * 128;
    const int col0 = (swz & 7) * 128;
    const int tid = threadIdx.x;
    const int wave = tid >> 6, lane = tid & 63;
    const int wr = wave >> 1, wc = wave & 1;
    const int lr = lane & 15, lk = lane >> 4;

    f32x4 acc[4][4];
#pragma unroll
    for (int m = 0; m < 4; ++m)
#pragma unroll
        for (int n = 0; n < 4; ++n)
#pragma unroll
            for (int r = 0; r < 4; ++r) acc[m][n][r] = 0.f;

    const int lrow = lane >> 2;
    const int lcol8 = (lane & 3) * 8;

    for (int k0 = 0; k0 < K; k0 += 32) {
#pragma unroll
        for (int e = 0; e < 2; ++e) {
            int cib = wave * 128 + e * 64;
            int row = (cib >> 2) + lrow;
            gload16(A  + (size_t)(row0 + row) * K + k0 + lcol8, &As[cib * 8]);
            gload16(WT + (size_t)(col0 + row) * K + k0 + lcol8, &Bs[cib * 8]);
        }
        __syncthreads();
        bf16x8 af[4], bff[4];
#pragma unroll
        for (int m = 0; m < 4; ++m)
            af[m] = *(const bf16x8*)&As[(wr * 64 + m * 16 + lr) * 32 + lk * 8];
#pragma unroll
        for (int n = 0; n < 4; ++n)
            bff[n] = *(const bf16x8*)&Bs[(wc * 64 + n * 16 + lr) * 32 + lk * 8];
#pragma unroll
        for (int m = 0; m < 4; ++m)
#pragma unroll
            for (int n = 0; n < 4; ++n)
                acc[m][n] = __builtin_amdgcn_mfma_f32_16x16x32_bf16(af[m], bff[n], acc[m][n], 0, 0, 0);
        __syncthreads();
    }

#pragma unroll
    for (int m = 0; m < 4; ++m)
#pragma unroll
        for (int n = 0; n < 4; ++n) {
            int col = col0 + wc * 64 + n * 16 + lr;
#pragma unroll
            for (int r = 0; r < 4; ++r) {
                int row = row0 + wr * 64 + m * 16 + lk * 4 + r;
                out[(size_t)row * N + col] = acc[m][n][r];
            }
        }
}

// ---------------------------------------------------------------------------
// stage-1 low-rank MFMA, fused (seg on blockIdx.x) — BM=64 for grid-fill
// (256 blocks). Each wave handles 16 rows.
// ---------------------------------------------------------------------------
__global__ __launch_bounds__(256) void lowrank1_fused(
    const float* __restrict__ x,
    const float* __restrict__ x_w, const float* __restrict__ x_a,
    const float* __restrict__ x_g,
    const unsigned short* __restrict__ w1t, const unsigned short* __restrict__ a1t,
    const unsigned short* __restrict__ g1t,
    unsigned short* __restrict__ hw, unsigned short* __restrict__ ha,
    unsigned short* __restrict__ hg)
{
    const int seg = blockIdx.x;
    const float* mix; const unsigned short* WT; unsigned short* out;
    int N, col0, epi;
    if (seg == 0)      { mix = x_w; WT = w1t; out = hw; N = 64;  col0 = 0; epi = 1; }
    else if (seg == 1) { mix = x_a; WT = a1t; out = ha; N = 64;  col0 = 0; epi = 0; }
    else               { mix = x_g; WT = g1t; out = hg; N = 128; col0 = (seg - 2) * 64; epi = 2; }

    __shared__ __attribute__((aligned(16))) unsigned short As[64][40];
    __shared__ __attribute__((aligned(16))) unsigned short Bs[64][40];
    const int row0 = blockIdx.y * 64;
    const int tid = threadIdx.x;
    const int wave = tid >> 6, lane = tid & 63;
    const int lr = lane & 15, lk = lane >> 4;

    f32x4 acc[4];
#pragma unroll
    for (int n = 0; n < 4; ++n)
#pragma unroll
        for (int r = 0; r < 4; ++r) acc[n][r] = 0.f;

    for (int k0 = 0; k0 < Cc; k0 += 32) {
        {
            int ar = tid >> 2, ac = (tid & 3) * 8;
            int row = row0 + ar;
            const float* xp = x + (size_t)row * Cc + k0 + ac;
            float4 c0 = *(const float4*)xp;
            float4 c1 = *(const float4*)(xp + 4);
            float4 p0, p1;
            if (row & (Tt - 1)) {
                p0 = *(const float4*)(xp - Cc);
                p1 = *(const float4*)(xp - Cc + 4);
            } else {
                p0.x = p0.y = p0.z = p0.w = 0.f;
                p1.x = p1.y = p1.z = p1.w = 0.f;
            }
            float4 m0 = *(const float4*)(mix + k0 + ac);
            float4 m1 = *(const float4*)(mix + k0 + ac + 4);
            const float* cf0 = (const float*)&c0; const float* cf1 = (const float*)&c1;
            const float* pf0 = (const float*)&p0; const float* pf1 = (const float*)&p1;
            const float* mf0 = (const float*)&m0; const float* mf1 = (const float*)&m1;
            ushort4 u0, u1;
            unsigned short* up0 = (unsigned short*)&u0;
            unsigned short* up1 = (unsigned short*)&u1;
#pragma unroll
            for (int j = 0; j < 4; ++j) {
                up0[j] = f2bf(cf0[j] + (pf0[j] - cf0[j]) * mf0[j]);
                up1[j] = f2bf(cf1[j] + (pf1[j] - cf1[j]) * mf1[j]);
            }
            *(ushort4*)&As[ar][ac] = u0;
            *(ushort4*)&As[ar][ac + 4] = u1;
        }
        {
            int br = tid >> 2, bc = (tid & 3) * 8;
            *(uint4*)&Bs[br][bc] = *(const uint4*)(WT + (size_t)(col0 + br) * Cc + k0 + bc);
        }
        __syncthreads();
        bf16x8 af, bff[4];
        af = *(const bf16x8*)&As[wave * 16 + lr][lk * 8];
#pragma unroll
        for (int n = 0; n < 4; ++n)
            bff[n] = *(const bf16x8*)&Bs[n * 16 + lr][lk * 8];
#pragma unroll
        for (int n = 0; n < 4; ++n)
            acc[n] = __builtin_amdgcn_mfma_f32_16x16x32_bf16(af, bff[n], acc[n], 0, 0, 0);
        __syncthreads();
    }

#pragma unroll
    for (int n = 0; n < 4; ++n) {
        int col = col0 + n * 16 + lr;
#pragma unroll
        for (int r = 0; r < 4; ++r) {
            int row = row0 + wave * 16 + lk * 4 + r;
            float v = acc[n][r];
            if (epi == 1) v = tanhf(v);
            else if (epi == 2) v = sigf(v);
            out[(size_t)row * N + col] = f2bf(v);
        }
    }
}

// ---------------------------------------------------------------------------
// stage-2 low-rank MFMA, fused. z0: wdb=decay -> bf16; z1: ab=sig -> f32;
// z2: gb -> bf16.
// ---------------------------------------------------------------------------
__global__ __launch_bounds__(256) void stage2_fused(
    const unsigned short* __restrict__ hw, const unsigned short* __restrict__ ha,
    const unsigned short* __restrict__ hg,
    const unsigned short* __restrict__ w2t, const unsigned short* __restrict__ a2t,
    const unsigned short* __restrict__ g2t,
    unsigned short* __restrict__ wdbh, float* __restrict__ abf,
    unsigned short* __restrict__ gb,
    const float* __restrict__ w0, const float* __restrict__ a0)
{
    const int z = blockIdx.z;
    const unsigned short* A  = z == 0 ? hw : z == 1 ? ha : hg;
    const unsigned short* WT = z == 0 ? w2t : z == 1 ? a2t : g2t;
    const float* bias = z == 0 ? w0 : z == 1 ? a0 : nullptr;
    const int K = (z == 2) ? 128 : 64;
    const int N = Cc;

    __shared__ __attribute__((aligned(16))) unsigned short As[128 * 32];
    __shared__ __attribute__((aligned(16))) unsigned short Bs[64 * 32];
    const int row0 = blockIdx.y * 128;
    const int col0 = blockIdx.x * 64;
    const int tid = threadIdx.x;
    const int wave = tid >> 6, lane = tid & 63;
    const int lr = lane & 15, lk = lane >> 4;

    f32x4 acc[2][4];
#pragma unroll
    for (int m = 0; m < 2; ++m)
#pragma unroll
        for (int n = 0; n < 4; ++n)
#pragma unroll
            for (int r = 0; r < 4; ++r) acc[m][n][r] = 0.f;

    const int lrow = lane >> 2;
    const int lcol8 = (lane & 3) * 8;

    for (int k0 = 0; k0 < K; k0 += 32) {
#pragma unroll
        for (int e = 0; e < 2; ++e) {
            int cib = wave * 128 + e * 64;
            int row = (cib >> 2) + lrow;
            gload16(A + (size_t)(row0 + row) * K + k0 + lcol8, &As[cib * 8]);
        }
        {
            int cib = wave * 64;
            int row = (cib >> 2) + lrow;
            gload16(WT + (size_t)(col0 + row) * K + k0 + lcol8, &Bs[cib * 8]);
        }
        __syncthreads();
        bf16x8 af[2], bff[4];
#pragma unroll
        for (int m = 0; m < 2; ++m)
            af[m] = *(const bf16x8*)&As[(wave * 32 + m * 16 + lr) * 32 + lk * 8];
#pragma unroll
        for (int n = 0; n < 4; ++n)
            bff[n] = *(const bf16x8*)&Bs[(n * 16 + lr) * 32 + lk * 8];
#pragma unroll
        for (int m = 0; m < 2; ++m)
#pragma unroll
            for (int n = 0; n < 4; ++n)
                acc[m][n] = __builtin_amdgcn_mfma_f32_16x16x32_bf16(af[m], bff[n], acc[m][n], 0, 0, 0);
        __syncthreads();
    }

#pragma unroll
    for (int m = 0; m < 2; ++m)
#pragma unroll
        for (int n = 0; n < 4; ++n) {
            int col = col0 + n * 16 + lr;
#pragma unroll
            for (int r = 0; r < 4; ++r) {
                int row = row0 + wave * 32 + m * 16 + lk * 4 + r;
                float v = acc[m][n][r];
                if (bias) v += bias[col];
                if (z == 0) {
                    v = expf(-0.60653065971263342f * sigf(v));
                    wdbh[(size_t)row * N + col] = f2bf(v);
                } else if (z == 1) {
                    abf[(size_t)row * N + col] = sigf(v);
                } else {
                    gb[(size_t)row * N + col] = f2bf(v);
                }
            }
        }
}

// ---------------------------------------------------------------------------
// WKV chunked, phase 1 (aa/bb computed inline from kraw/abf/k_k during staging;
// k_final computed inline in C-task; A_l dumped to global bf16).
// NOTE: k_k and k_a are per-ABSOLUTE-channel (1024) vectors: index h*HSs + off.
// ---------------------------------------------------------------------------
__global__ __launch_bounds__(256, 1) void wkv_chunk1(
    const unsigned short* __restrict__ rbh, const unsigned short* __restrict__ wdbh,
    const unsigned short* __restrict__ kraw, const float* __restrict__ abf,
    const float* __restrict__ k_k, const float* __restrict__ k_a,
    unsigned short* __restrict__ TLt,  // [blk][j=64][p=64]
    unsigned short* __restrict__ Rho,  // [blk][t=32][p=64]
    unsigned short* __restrict__ ZLt,  // [blk][j=64][s=32]
    unsigned short* __restrict__ Alh)  // [blk][t=32][s=32]
{
    __shared__ float st[CL * STRD];    // arrays: 0=aa 1=wd 2=bb 3=r
    __shared__ float A_l[CL][CL + 1];
    const int blk = blockIdx.x;
    const int bh = blk >> 5;
    const int c  = blk & (NCH - 1);
    const int b = bh >> 4, h = bh & 15;
    const size_t base = (size_t)b * Tt * Cc + h * HSs + (size_t)c * CL * Cc;
    const int tid = threadIdx.x;

    // ---- stage: wd,r direct; aa,bb computed (head-norm via 8-lane reduce) ----
    {
        const int s = tid >> 3, j8 = (tid & 7) * 8;
        const size_t go = base + (size_t)s * Cc + j8;
        // wd
        {
            uint4 u = *(const uint4*)(wdbh + go);
            const unsigned int* q = (const unsigned int*)&u;
            float4 f0, f1;
            f0.x = __uint_as_float(q[0] << 16); f0.y = __uint_as_float(q[0] & 0xFFFF0000u);
            f0.z = __uint_as_float(q[1] << 16); f0.w = __uint_as_float(q[1] & 0xFFFF0000u);
            f1.x = __uint_as_float(q[2] << 16); f1.y = __uint_as_float(q[2] & 0xFFFF0000u);
            f1.z = __uint_as_float(q[3] << 16); f1.w = __uint_as_float(q[3] & 0xFFFF0000u);
            *(float4*)&st[s * STRD + 1 * 64 + j8] = f0;
            *(float4*)&st[s * STRD + 1 * 64 + j8 + 4] = f1;
        }
        // r
        {
            uint4 u = *(const uint4*)(rbh + go);
            const unsigned int* q = (const unsigned int*)&u;
            float4 f0, f1;
            f0.x = __uint_as_float(q[0] << 16); f0.y = __uint_as_float(q[0] & 0xFFFF0000u);
            f0.z = __uint_as_float(q[1] << 16); f0.w = __uint_as_float(q[1] & 0xFFFF0000u);
            f1.x = __uint_as_float(q[2] << 16); f1.y = __uint_as_float(q[2] & 0xFFFF0000u);
            f1.z = __uint_as_float(q[3] << 16); f1.w = __uint_as_float(q[3] & 0xFFFF0000u);
            *(float4*)&st[s * STRD + 3 * 64 + j8] = f0;
            *(float4*)&st[s * STRD + 3 * 64 + j8 + 4] = f1;
        }
        // aa/bb from kraw * k_k (head-norm), a from fp32 abf
        float kr[8];
        {
            uint4 u = *(const uint4*)(kraw + go);
            UNPK8(kr, u, 0);
        }
        float4 av0 = *(const float4*)(abf + go);
        float4 av1 = *(const float4*)(abf + go + 4);
        const float* avp0 = (const float*)&av0;
        const float* avp1 = (const float*)&av1;
        const int ch0 = h * HSs + j8;          // ABSOLUTE channel
        float4 kk0 = *(const float4*)(k_k + ch0);
        float4 kk1 = *(const float4*)(k_k + ch0 + 4);
        const float* kkw = (const float*)&kk0;
        const float* kkw1 = (const float*)&kk1;
        float kkv[8];
#pragma unroll
        for (int j = 0; j < 4; ++j) {
            kkv[j] = kr[j] * kkw[j];
            kkv[4 + j] = kr[4 + j] * kkw1[j];
        }
        float ssq = 0.f;
#pragma unroll
        for (int j = 0; j < 8; ++j) ssq = fmaf(kkv[j], kkv[j], ssq);
        ssq = dpp_add_xor1(ssq);
        ssq = dpp_add_xor2(ssq);
        ssq += __shfl_xor(ssq, 4);
        float inv = 1.f / fmaxf(sqrtf(ssq), 1e-12f);
        float4 aa0, aa1, bb0, bb1;
        float* aap = (float*)&aa0; float* bbp = (float*)&bb0;
#pragma unroll
        for (int j = 0; j < 4; ++j) {
            float kkn = kkv[j] * inv;
            aap[j] = -kkn;
            bbp[j] = kkn * avp0[j];
        }
        float* aq = (float*)&aa1; float* bq = (float*)&bb1;
#pragma unroll
        for (int j = 0; j < 4; ++j) {
            float kkn = kkv[4 + j] * inv;
            aq[j] = -kkn;
            bq[j] = kkn * avp1[j];
        }
        *(float4*)&st[s * STRD + 0 * 64 + j8] = aa0;
        *(float4*)&st[s * STRD + 0 * 64 + j8 + 4] = aa1;
        *(float4*)&st[s * STRD + 2 * 64 + j8] = bb0;
        *(float4*)&st[s * STRD + 2 * 64 + j8 + 4] = bb1;
    }
    __syncthreads();

    const int wv = tid >> 6, lane = tid & 63;
    if (wv < 2) {
        // ---- B-task: 2 rows x 16 cols per thread, 2 waves = 64 rows ----
        const int idx = wv * 64 + lane;
        const int rq = idx >> 2, jc = idx & 3;
        const int i0 = rq * 2, j0 = jc * 16;
        float T[2][16];
#pragma unroll
        for (int rr = 0; rr < 2; ++rr)
#pragma unroll
            for (int cc = 0; cc < 16; ++cc)
                T[rr][cc] = (i0 + rr == j0 + cc) ? 1.f : 0.f;
        const size_t rhob = (size_t)blk * (CL * 64);

        for (int t = 0; t < CL; ++t) {
            const float* sp = st + t * STRD;
            float a[16], w[16], bv[16], r[16];
#pragma unroll
            for (int q = 0; q < 4; ++q) {
                *(float4*)&a[q * 4]  = *(const float4*)(sp + 0 * 64 + j0 + q * 4);
                *(float4*)&w[q * 4]  = *(const float4*)(sp + 1 * 64 + j0 + q * 4);
                *(float4*)&bv[q * 4] = *(const float4*)(sp + 2 * 64 + j0 + q * 4);
                *(float4*)&r[q * 4]  = *(const float4*)(sp + 3 * 64 + j0 + q * 4);
            }
            float ta[2];
#pragma unroll
            for (int rr = 0; rr < 2; ++rr) {
                float q0 = T[rr][0] * a[0], q1 = T[rr][4] * a[4];
                float q2 = T[rr][8] * a[8], q3 = T[rr][12] * a[12];
#pragma unroll
                for (int e = 1; e < 4; ++e) {
                    q0 = fmaf(T[rr][e], a[e], q0);
                    q1 = fmaf(T[rr][4 + e], a[4 + e], q1);
                    q2 = fmaf(T[rr][8 + e], a[8 + e], q2);
                    q3 = fmaf(T[rr][12 + e], a[12 + e], q3);
                }
                ta[rr] = (q0 + q1) + (q2 + q3);
            }
#pragma unroll
            for (int rr = 0; rr < 2; ++rr) {
                ta[rr] = dpp_add_xor1(ta[rr]);
                ta[rr] = dpp_add_xor2(ta[rr]);
            }
            float rp[2];
#pragma unroll
            for (int rr = 0; rr < 2; ++rr) {
                float q0 = 0.f, q1 = 0.f, q2 = 0.f, q3 = 0.f;
#pragma unroll
                for (int e = 0; e < 4; ++e) {
                    T[rr][e]      = fmaf(T[rr][e],      w[e],      ta[rr] * bv[e]);
                    T[rr][4 + e]  = fmaf(T[rr][4 + e],  w[4 + e],  ta[rr] * bv[4 + e]);
                    T[rr][8 + e]  = fmaf(T[rr][8 + e],  w[8 + e],  ta[rr] * bv[8 + e]);
                    T[rr][12 + e] = fmaf(T[rr][12 + e], w[12 + e], ta[rr] * bv[12 + e]);
                    q0 = fmaf(T[rr][e], r[e], q0);
                    q1 = fmaf(T[rr][4 + e], r[4 + e], q1);
                    q2 = fmaf(T[rr][8 + e], r[8 + e], q2);
                    q3 = fmaf(T[rr][12 + e], r[12 + e], q3);
                }
                rp[rr] = (q0 + q1) + (q2 + q3);
            }
#pragma unroll
            for (int rr = 0; rr < 2; ++rr) {
                rp[rr] = dpp_add_xor1(rp[rr]);
                rp[rr] = dpp_add_xor2(rp[rr]);
            }
            if (jc == 0) {
                ushort2 o2;
                o2.x = f2bf(rp[0]); o2.y = f2bf(rp[1]);
                *(ushort2*)(Rho + rhob + t * 64 + i0) = o2;
            }
        }
        const size_t tlb = (size_t)blk * 4096;
#pragma unroll
        for (int cc = 0; cc < 16; ++cc) {
            ushort2 o2;
            o2.x = f2bf(T[0][cc]); o2.y = f2bf(T[1][cc]);
            *(ushort2*)(TLt + tlb + (size_t)(j0 + cc) * 64 + i0) = o2;
        }
    } else {
        // ---- C-task: 1 s x 16 cols per thread; k_final computed inline ----
        const int idx2 = (wv - 2) * 64 + lane;
        const int s = idx2 >> 2, q4 = idx2 & 3;
        const int j0 = q4 * 16;
        float kreg[16];
        {
            float kr[16];
            uint4 u0 = *(const uint4*)(kraw + base + (size_t)s * Cc + j0);
            uint4 u1 = *(const uint4*)(kraw + base + (size_t)s * Cc + j0 + 8);
            UNPK8(kr, u0, 0); UNPK8(kr, u1, 8);
#pragma unroll
            for (int q = 0; q < 4; ++q) {
                float4 av4 = *(const float4*)(abf + base + (size_t)s * Cc + j0 + q * 4);
                float4 ka4 = *(const float4*)(k_a + h * HSs + j0 + q * 4);   // ABSOLUTE channel
                const float* avp = (const float*)&av4;
                const float* kap = (const float*)&ka4;
#pragma unroll
                for (int e = 0; e < 4; ++e) {
                    int u = q * 4 + e;
                    kreg[u] = kr[u] * (1.f + (avp[e] - 1.f) * kap[e]);
                }
            }
        }
        float z[16];
#pragma unroll
        for (int u = 0; u < 16; ++u) z[u] = 0.f;

        for (int t = 0; t < CL; ++t) {
            const float* sp = st + t * STRD;
            float a[16], w[16], bv[16], r[16];
#pragma unroll
            for (int q = 0; q < 4; ++q) {
                *(float4*)&a[q * 4]  = *(const float4*)(sp + 0 * 64 + j0 + q * 4);
                *(float4*)&w[q * 4]  = *(const float4*)(sp + 1 * 64 + j0 + q * 4);
                *(float4*)&bv[q * 4] = *(const float4*)(sp + 2 * 64 + j0 + q * 4);
                *(float4*)&r[q * 4]  = *(const float4*)(sp + 3 * 64 + j0 + q * 4);
            }
            float q0 = z[0] * a[0], q1 = z[4] * a[4];
            float q2 = z[8] * a[8], q3 = z[12] * a[12];
#pragma unroll
            for (int e = 1; e < 4; ++e) {
                q0 = fmaf(z[e], a[e], q0);
                q1 = fmaf(z[4 + e], a[4 + e], q1);
                q2 = fmaf(z[8 + e], a[8 + e], q2);
                q3 = fmaf(z[12 + e], a[12 + e], q3);
            }
            float za = (q0 + q1) + (q2 + q3);
            za = dpp_add_xor1(za);
            za = dpp_add_xor2(za);
#pragma unroll
            for (int u = 0; u < 16; ++u)
                z[u] = fmaf(z[u], w[u], za * bv[u]);
            if (s == t) {
#pragma unroll
                for (int u = 0; u < 16; ++u) z[u] = kreg[u];
            }
            float p0 = z[0] * r[0], p1 = z[4] * r[4];
            float p2 = z[8] * r[8], p3 = z[12] * r[12];
#pragma unroll
            for (int e = 1; e < 4; ++e) {
                p0 = fmaf(z[e], r[e], p0);
                p1 = fmaf(z[4 + e], r[4 + e], p1);
                p2 = fmaf(z[8 + e], r[8 + e], p2);
                p3 = fmaf(z[12 + e], r[12 + e], p3);
            }
            float al = (p0 + p1) + (p2 + p3);
            al = dpp_add_xor1(al);
            al = dpp_add_xor2(al);
            if (q4 == 0) A_l[t][s] = al;
        }
        const size_t zlb = (size_t)blk * (CL * 64);
#pragma unroll
        for (int u = 0; u < 16; ++u)
            ZLt[zlb + (size_t)(j0 + u) * 32 + s] = f2bf(z[u]);
    }
    __syncthreads();

    // ---- dump A_l -> Alh (bf16, [t][s], coalesced) ----
    if (tid < 128) {
        const int t = tid >> 2, s8 = (tid & 3) * 8;
        ushort4 o0, o1;
        unsigned short* p0 = (unsigned short*)&o0;
        unsigned short* p1 = (unsigned short*)&o1;
#pragma unroll
        for (int e = 0; e < 4; ++e) {
            p0[e] = f2bf(A_l[t][s8 + e]);
            p1[e] = f2bf(A_l[t][s8 + 4 + e]);
        }
        unsigned short* dst = Alh + (size_t)blk * 1024 + t * 32 + s8;
        *(ushort4*)dst = o0;
        *(ushort4*)(dst + 4) = o1;
    }
}

// ---------------------------------------------------------------------------
// WKV chunked, phase 2 — MFMA; y = S0·rho + V^T·A_l (pure store, fp32 out).
// ---------------------------------------------------------------------------
__global__ __launch_bounds__(256, 1) void wkv_chunk2(
    const unsigned short* __restrict__ vbh, const unsigned short* __restrict__ TLt,
    const unsigned short* __restrict__ Rho, const unsigned short* __restrict__ ZLt,
    const unsigned short* __restrict__ Alh, float* __restrict__ yb)
{
    __shared__ unsigned short Sl[64 * 72];
    __shared__ unsigned short Ttl[64 * 72];
    __shared__ unsigned short Ztl[64 * 40];
    __shared__ unsigned short Rl[32 * 72];
    __shared__ unsigned short Vtl[64 * 40];
    __shared__ unsigned short All[32 * 40];
    const int bh = blockIdx.x;
    const size_t vbase = (size_t)(bh >> 4) * Tt * Cc + (bh & 15) * HSs;
    const int tid = threadIdx.x;
    const int wv = tid >> 6, lane = tid & 63;
    const int lr = lane & 15, lk = lane >> 4;
    const int i0w = wv * 16;

    f32x4 S[4];
#pragma unroll
    for (int n = 0; n < 4; ++n)
#pragma unroll
        for (int r = 0; r < 4; ++r) S[n][r] = 0.f;

    uint4 pT0, pT1, pZ, pR, pAl, pVu;
    const int vs = tid >> 3, vi0 = (tid & 7) * 8;

#define C2_LOAD(c_) do { \
    size_t cb_ = (size_t)(bh * NCH + (c_)); \
    const uint4* tp_ = (const uint4*)(TLt + cb_ * 4096); \
    pT0 = tp_[tid * 2]; pT1 = tp_[tid * 2 + 1]; \
    pZ = ((const uint4*)(ZLt + cb_ * 2048))[tid]; \
    pR = ((const uint4*)(Rho + cb_ * 2048))[tid]; \
    if (tid < 128) pAl = ((const uint4*)(Alh + cb_ * 1024))[tid]; \
    pVu = *(const uint4*)(vbh + vbase + (size_t)((c_) * CL + vs) * Cc + vi0); \
} while (0)

#define C2_STORE() do { \
    *(uint4*)&Ttl[(tid >> 2) * 72 + (tid & 3) * 16] = pT0; \
    *(uint4*)&Ttl[(tid >> 2) * 72 + (tid & 3) * 16 + 8] = pT1; \
    *(uint4*)&Ztl[(tid >> 2) * 40 + (tid & 3) * 8] = pZ; \
    *(uint4*)&Rl[(tid >> 3) * 72 + (tid & 7) * 8] = pR; \
    if (tid < 128) *(uint4*)&All[(tid >> 2) * 40 + (tid & 3) * 8] = pAl; \
    const unsigned short* pvu_ = (const unsigned short*)&pVu; \
    Vtl[(vi0 + 0) * 40 + vs] = pvu_[0]; \
    Vtl[(vi0 + 1) * 40 + vs] = pvu_[1]; \
    Vtl[(vi0 + 2) * 40 + vs] = pvu_[2]; \
    Vtl[(vi0 + 3) * 40 + vs] = pvu_[3]; \
    Vtl[(vi0 + 4) * 40 + vs] = pvu_[4]; \
    Vtl[(vi0 + 5) * 40 + vs] = pvu_[5]; \
    Vtl[(vi0 + 6) * 40 + vs] = pvu_[6]; \
    Vtl[(vi0 + 7) * 40 + vs] = pvu_[7]; \
} while (0)

    C2_LOAD(0);
    for (int c = 0; c < NCH; ++c) {
        __syncthreads();
#pragma unroll
        for (int n = 0; n < 4; ++n) {
#pragma unroll
            for (int r = 0; r < 4; ++r)
                Sl[(i0w + lk * 4 + r) * 72 + n * 16 + lr] = f2bf(S[n][r]);
        }
        C2_STORE();
        if (c + 1 < NCH) C2_LOAD(c + 1);
        __syncthreads();

        bf16x8 sA0 = *(const bf16x8*)&Sl[(i0w + lr) * 72 + lk * 8];
        bf16x8 sA1 = *(const bf16x8*)&Sl[(i0w + lr) * 72 + 32 + lk * 8];
        bf16x8 vA = *(const bf16x8*)&Vtl[(i0w + lr) * 40 + lk * 8];

#pragma unroll
        for (int nt = 0; nt < 2; ++nt) {
            int t = nt * 16 + lr;
            float* yp = yb + vbase + (size_t)(c * CL + t) * Cc + i0w + lk * 4;
            f32x4 yc = { 0.f, 0.f, 0.f, 0.f };
            bf16x8 b0 = *(const bf16x8*)&Rl[t * 72 + lk * 8];
            bf16x8 b1 = *(const bf16x8*)&Rl[t * 72 + 32 + lk * 8];
            bf16x8 al8 = *(const bf16x8*)&All[t * 40 + lk * 8];
            yc = __builtin_amdgcn_mfma_f32_16x16x32_bf16(sA0, b0, yc, 0, 0, 0);
            yc = __builtin_amdgcn_mfma_f32_16x16x32_bf16(sA1, b1, yc, 0, 0, 0);
            yc = __builtin_amdgcn_mfma_f32_16x16x32_bf16(vA, al8, yc, 0, 0, 0);
            *(f32x4*)yp = yc;
        }

#pragma unroll
        for (int n = 0; n < 4; ++n) {
            int j = n * 16 + lr;
            bf16x8 t0 = *(const bf16x8*)&Ttl[j * 72 + lk * 8];
            bf16x8 t1 = *(const bf16x8*)&Ttl[j * 72 + 32 + lk * 8];
            bf16x8 z0 = *(const bf16x8*)&Ztl[j * 40 + lk * 8];
            f32x4 acc = { 0.f, 0.f, 0.f, 0.f };
            acc = __builtin_amdgcn_mfma_f32_16x16x32_bf16(sA0, t0, acc, 0, 0, 0);
            acc = __builtin_amdgcn_mfma_f32_16x16x32_bf16(sA1, t1, acc, 0, 0, 0);
            acc = __builtin_amdgcn_mfma_f32_16x16x32_bf16(vA, z0, acc, 0, 0, 0);
            S[n] = acc;
        }
    }
#undef C2_LOAD
#undef C2_STORE
}

// ---------------------------------------------------------------------------
// GroupNorm + r*k*r_k bonus + gate; y fp32, k_final inline from bf16 kraw +
// fp32 abf
// ---------------------------------------------------------------------------
__global__ __launch_bounds__(256) void gn_rt_kernel(
    const float* __restrict__ yb, const unsigned short* __restrict__ rbh,
    const unsigned short* __restrict__ kraw, const float* __restrict__ abf,
    const unsigned short* __restrict__ vbh,
    const unsigned short* __restrict__ gb, const float* __restrict__ r_k,
    const float* __restrict__ k_a,
    const float* __restrict__ ln_w, const float* __restrict__ ln_b,
    unsigned short* __restrict__ zb)
{
    const int row = blockIdx.x;
    const int tid = threadIdx.x;
    const int c0 = tid * 4;
    const int hd = tid >> 4;
    const int n0 = c0 & 63;
    const size_t o = (size_t)row * Cc;

    float4 y4 = *(const float4*)(yb + o + c0);
    ushort4 r4u = *(const ushort4*)(rbh + o + c0);
    ushort4 k4u = *(const ushort4*)(kraw + o + c0);
    float4 a4 = *(const float4*)(abf + o + c0);
    ushort4 v4u = *(const ushort4*)(vbh + o + c0);
    ushort4 g4u = *(const ushort4*)(gb + o + c0);
    float4 rk4 = *(const float4*)(r_k + hd * 64 + n0);
    float4 ka4 = *(const float4*)(k_a + c0);

    float yv[4] = { y4.x, y4.y, y4.z, y4.w };
    float rv[4] = { bf2f(r4u.x), bf2f(r4u.y), bf2f(r4u.z), bf2f(r4u.w) };
    float krv[4] = { bf2f(k4u.x), bf2f(k4u.y), bf2f(k4u.z), bf2f(k4u.w) };
    const float* avp = (const float*)&a4;
    float vv[4] = { bf2f(v4u.x), bf2f(v4u.y), bf2f(v4u.z), bf2f(v4u.w) };
    float gv[4] = { bf2f(g4u.x), bf2f(g4u.y), bf2f(g4u.z), bf2f(g4u.w) };
    float rkv[4] = { rk4.x, rk4.y, rk4.z, rk4.w };
    const float* kap = (const float*)&ka4;

    float kv[4];
#pragma unroll
    for (int j = 0; j < 4; ++j)
        kv[j] = krv[j] * (1.f + (avp[j] - 1.f) * kap[j]);

    float sum = 0.f, ssq = 0.f, dot = 0.f;
#pragma unroll
    for (int j = 0; j < 4; ++j) {
        sum += yv[j];
        ssq += yv[j] * yv[j];
        dot += rv[j] * kv[j] * rkv[j];
    }
#pragma unroll
    for (int m = 1; m <= 8; m <<= 1) {
        sum += __shfl_xor(sum, m);
        ssq += __shfl_xor(ssq, m);
        dot += __shfl_xor(dot, m);
    }
    const float mu = sum * (1.f / 64.f);
    const float var = ssq * (1.f / 64.f) - mu * mu;
    const float inv = rsqrtf(var + 0.00064f);

    ushort4 z4;
    unsigned short* zp = (unsigned short*)&z4;
#pragma unroll
    for (int j = 0; j < 4; ++j) {
        int c = c0 + j;
        float yg = (yv[j] - mu) * inv * ln_w[c] + ln_b[c];
        yg += dot * vv[j];
        zp[j] = f2bf(yg * gv[j]);
    }
    *(ushort4*)(zb + o + c0) = z4;
}

// ---------------------------------------------------------------------------

extern "C" void kernel_launch(void* const* d_in, const int* in_sizes, int n_in,
                              void* d_out, int out_size, void* d_ws, size_t ws_size,
                              hipStream_t stream)
{
    const float* x   = (const float*)d_in[0];
    const float* x_r = (const float*)d_in[1];
    const float* x_w = (const float*)d_in[2];
    const float* x_k = (const float*)d_in[3];
    const float* x_v = (const float*)d_in[4];
    const float* x_a = (const float*)d_in[5];
    const float* x_g = (const float*)d_in[6];
    const float* w0  = (const float*)d_in[7];
    const float* w1  = (const float*)d_in[8];
    const float* w2  = (const float*)d_in[9];
    const float* a0  = (const float*)d_in[10];
    const float* a1  = (const float*)d_in[11];
    const float* a2  = (const float*)d_in[12];
    // v0,v1,v2 (13..15): forward no-op on first-layer call
    const float* g1  = (const float*)d_in[16];
    const float* g2  = (const float*)d_in[17];
    const float* k_k = (const float*)d_in[18];
    const float* k_a = (const float*)d_in[19];
    const float* r_k = (const float*)d_in[20];
    const float* Wr  = (const float*)d_in[21];
    const float* Wk  = (const float*)d_in[22];
    const float* Wv  = (const float*)d_in[23];
    const float* Wo  = (const float*)d_in[24];
    const float* ln_w = (const float*)d_in[25];
    const float* ln_b = (const float*)d_in[26];

    float* ws = (float*)d_ws;
    const size_t S = (size_t)Bsz * Tt * Cc;       // 4,194,304 elements
    const int M = Bsz * Tt;                        // 4096

    // slot0: rbh (bf16, 8MB) + zb (bf16, 8MB)
    unsigned short* rbh = (unsigned short*)(ws + 0 * S);
    unsigned short* zb  = (unsigned short*)ws + S;
    // slot1: wdbh + gb
    unsigned short* wdbh = (unsigned short*)(ws + 1 * S);
    unsigned short* gb  = (unsigned short*)(ws + 1 * S) + S;
    // slot2: kbh (kraw) + vbh
    unsigned short* kbh = (unsigned short*)(ws + 2 * S);
    unsigned short* vbh = (unsigned short*)(ws + 2 * S) + S;
    // slot3: abf (fp32, 16MB)
    float* abf = ws + 3 * S;
    // slot4: yb (fp32, 16MB)
    float* yb = ws + 4 * S;
    // slot5: xr + xk -> Rho + ZLt after gemm_rkv
    unsigned short* xr = (unsigned short*)(ws + 5 * S);
    unsigned short* xk = (unsigned short*)(ws + 5 * S) + S;
    unsigned short* Rho = xr;
    unsigned short* ZLt = xk;
    // slot6: xv (8MB) + h-buffers + small weight transposes
    unsigned short* xv = (unsigned short*)(ws + 6 * S);
    unsigned short* hw = xv + S;
    unsigned short* ha = hw + 262144;
    unsigned short* hg = ha + 262144;
    unsigned short* w1t = hg + 524288;
    unsigned short* a1t = w1t + 65536;
    unsigned short* g1t = a1t + 65536;
    unsigned short* w2t = g1t + 131072;
    unsigned short* a2t = w2t + 65536;
    unsigned short* g2t = a2t + 65536;
    // slot7: WrT/WkT/WvT/WoT (2MB each) + Alh (4MB)
    unsigned short* WrT = (unsigned short*)(ws + 7 * S);
    unsigned short* WkT = WrT + 1048576;
    unsigned short* WvT = WkT + 1048576;
    unsigned short* WoT = WvT + 1048576;
    unsigned short* Alh = WoT + 1048576;
    // slot8: TLt (16MB)
    unsigned short* TLt = (unsigned short*)(ws + 8 * S);

    dim3 blk(256);

    // 1. prep: mixcast + weight transposes
    prep_all<<<dim3(4096 + 1024 + 128), blk, 0, stream>>>(
        x, x_r, x_k, x_v, Wr, Wk, Wv, Wo, w1, a1, g1, w2, a2, g2,
        xr, xk, xv, WrT, WkT, WvT, WoT, w1t, a1t, g1t, w2t, a2t, g2t);

    // 2. stage-1 low-rank (BM=64: 256 blocks fills the chip)
    lowrank1_fused<<<dim3(4, 64), blk, 0, stream>>>(x, x_w, x_a, x_g, w1t, a1t, g1t, hw, ha, hg);

    // 3. r/k/v projections (all bf16 out; k stays raw), XCD-swizzled
    gemm_rkv<<<dim3(8, 32, 3), blk, 0, stream>>>(xr, xk, xv, WrT, WkT, WvT, rbh, kbh, vbh);

    // 4. stage-2 low-rank (wd/g bf16, ab fp32)
    stage2_fused<<<dim3(16, 32, 3), blk, 0, stream>>>(hw, ha, hg, w2t, a2t, g2t, wdbh, abf, gb, w0, a0);

    // 5-6. chunked recurrence (aa/bb/k_final computed inline)
    wkv_chunk1<<<dim3(64 * NCH), dim3(256), 0, stream>>>(rbh, wdbh, kbh, abf, k_k, k_a, TLt, Rho, ZLt, Alh);
    wkv_chunk2<<<dim3(64), blk, 0, stream>>>(vbh, TLt, Rho, ZLt, Alh, yb);

    // 7. groupnorm + bonus + gate (k_final inline)
    gn_rt_kernel<<<dim3(M), blk, 0, stream>>>(yb, rbh, kbh, abf, vbh, gb, r_k, k_a, ln_w, ln_b, zb);

    // 8. output projection (XCD-swizzled)
    gemm_bf16<<<dim3(8, 32), blk, 0, stream>>>(zb, WoT, (float*)d_out, M, Cc, Cc);
}